// Round 10
// baseline (427.374 us; speedup 1.0000x reference)
//
#include <hip/hip_runtime.h>
#include <hip/hip_cooperative_groups.h>

namespace cg = cooperative_groups;

// EnhanceCls: 2 segmented MLP passes (64x128 dbuf GEMM tiles, fused BN-stats,
// BN+leaky fused into GEMM2 A-staging, parallel colfin) + ONE cooperative
// tail kernel (colfin2-BC, mlp_out-BC, dist, enh, ep, cos, walk with
// grid.sync between phases). C=5 S=5 Q=75 P=196 D=384 K=30.

#define CC 5
#define SS 5
#define QQ 75
#define PP 196
#define DD 384
#define KK 30
#define QP (QQ * PP)   // 14700

typedef short bf16x8 __attribute__((ext_vector_type(8)));
typedef float f32x4  __attribute__((ext_vector_type(4)));
typedef unsigned short us16x4 __attribute__((ext_vector_type(4)));
typedef unsigned short us16x8 __attribute__((ext_vector_type(8)));
typedef unsigned short u16;

struct SegDesc { int b0, b1; float invM; };

__device__ __forceinline__ u16 f2bf(float f) {
    unsigned u = __float_as_uint(f);
    unsigned r = (u + 0x7fffu + ((u >> 16) & 1u)) >> 16;
    return (u16)r;
}
__device__ __forceinline__ float bf2f(u16 h) {
    return __uint_as_float((unsigned)h << 16);
}

__device__ __forceinline__ void lds_load16(const u16* g, u16* s) {
    __builtin_amdgcn_global_load_lds(
        (const __attribute__((address_space(1))) unsigned int*)g,
        (__attribute__((address_space(3))) unsigned int*)s, 16, 0, 0);
}

// XCD-aware decode: the 3 n-blocks of one m-block share bid%8 (same XCD).
__device__ __forceinline__ bool grid_decode(int mb, int& mblk, int& nb) {
    int bid = blockIdx.x;
    int g = bid / 24, t24 = bid - g * 24;
    nb = t24 >> 3;
    mblk = g * 8 + (t24 & 7);
    return mblk < mb;
}

// 64x128 tile: wave (wr,wc) computes rows wr*32..+32, cols wc*64..+64.
__device__ __forceinline__ void do_mfma64(const u16* Asb, const u16* Bsb,
                                          int wr, int wc, int l, f32x4 (&acc)[2][4]) {
#pragma unroll
    for (int ks = 0; ks < 2; ++ks) {
        bf16x8 af[2], bg[4];
#pragma unroll
        for (int i = 0; i < 2; ++i) {
            int rm = wr * 32 + i * 16 + (l & 15);
            af[i] = *(const bf16x8*)&Asb[rm * 64 + (((ks << 2) + (l >> 4)) ^ (rm & 7)) * 8];
        }
#pragma unroll
        for (int j = 0; j < 4; ++j) {
            int rn = wc * 64 + j * 16 + (l & 15);
            bg[j] = *(const bf16x8*)&Bsb[rn * 64 + (((ks << 2) + (l >> 4)) ^ (rn & 7)) * 8];
        }
#pragma unroll
        for (int i = 0; i < 2; ++i)
#pragma unroll
            for (int j = 0; j < 4; ++j)
                acc[i][j] = __builtin_amdgcn_mfma_f32_16x16x32_bf16(af[i], bg[j], acc[i][j], 0, 0, 0);
    }
}

// ---- weight prep: 4 matrices, Wt[m][n*384+k] = bf16(W[m][k*384+n]) ----
__global__ void prep_w4(const float* __restrict__ W0, const float* __restrict__ W1,
                        const float* __restrict__ W2, const float* __restrict__ W3,
                        u16* __restrict__ Wt) {
    int idx = blockIdx.x * 256 + threadIdx.x;      // 4 * 147456
    int m = idx / (DD * DD);
    int rem = idx - m * (DD * DD);
    int n = rem / DD, k = rem - n * DD;
    const float* W = (m == 0) ? W0 : (m == 1) ? W1 : (m == 2) ? W2 : W3;
    Wt[idx] = f2bf(W[k * DD + n]);
}

// ---- GEMM1: H(bf16) = bf16(A_f32) * B; 64x128 tile, dbuf pipeline ----
__global__ __launch_bounds__(256) void gemmF(const float* __restrict__ s0p,
                                             const float* __restrict__ s1p,
                                             const float* __restrict__ s2p,
                                             int rb0, int rb1, int M0, int M1, int M2,
                                             const u16* __restrict__ Bt,
                                             u16* __restrict__ H,
                                             float* __restrict__ partial, int mb) {
    __shared__ __align__(16) u16 As[2][4096];   // 64x64
    __shared__ __align__(16) u16 Bs[2][8192];   // 128x64
    __shared__ float sred[2][2][64][2];
    int mblk, nb;
    if (!grid_decode(mb, mblk, nb)) return;
    const int m0 = mblk * 64, n0 = nb * 128;
    const int tid = threadIdx.x;
    const int w = tid >> 6, l = tid & 63;
    const int wr = w >> 1, wc = w & 1;
    const int lr8 = l >> 3, kpB = l & 7;              // B staging coords
    const int arow = tid >> 2, kp0 = (tid & 3) * 2;   // A staging: 2 chunks/thread
    const int aslot0 = kp0 ^ (arow & 7);

    const int seg = (m0 >= rb0) + (m0 >= rb1);
    const float* src = seg == 0 ? s0p : seg == 1 ? s1p : s2p;
    const int segbase = seg == 0 ? 0 : seg == 1 ? rb0 : rb1;
    const int Mseg = seg == 0 ? M0 : seg == 1 ? M1 : M2;
    const int rloc = m0 - segbase + arow;

    f32x4 acc[2][4];
#pragma unroll
    for (int i = 0; i < 2; ++i)
#pragma unroll
        for (int j = 0; j < 4; ++j) acc[i][j] = f32x4{0.f, 0.f, 0.f, 0.f};

    f32x4 ra[4];
    auto issueA = [&](int kta) {
#pragma unroll
        for (int i = 0; i < 4; ++i) ra[i] = f32x4{0.f, 0.f, 0.f, 0.f};
        if (rloc < Mseg) {
            const f32x4* sp = (const f32x4*)(src + (size_t)rloc * DD + kta * 64 + kp0 * 8);
#pragma unroll
            for (int i = 0; i < 4; ++i) ra[i] = sp[i];
        }
    };
    auto stageB = [&](int kta, int b) {
#pragma unroll
        for (int i = 0; i < 4; ++i) {
            int row = i * 32 + w * 8 + lr8;
            lds_load16(Bt + (size_t)(n0 + row) * DD + kta * 64 + (kpB ^ (row & 7)) * 8,
                       &Bs[b][i * 2048 + w * 512]);
        }
    };
    auto writeA = [&](int b) {
        us16x8 o0, o1;
        o0[0] = f2bf(ra[0].x); o0[1] = f2bf(ra[0].y); o0[2] = f2bf(ra[0].z); o0[3] = f2bf(ra[0].w);
        o0[4] = f2bf(ra[1].x); o0[5] = f2bf(ra[1].y); o0[6] = f2bf(ra[1].z); o0[7] = f2bf(ra[1].w);
        o1[0] = f2bf(ra[2].x); o1[1] = f2bf(ra[2].y); o1[2] = f2bf(ra[2].z); o1[3] = f2bf(ra[2].w);
        o1[4] = f2bf(ra[3].x); o1[5] = f2bf(ra[3].y); o1[6] = f2bf(ra[3].z); o1[7] = f2bf(ra[3].w);
        *(us16x8*)&As[b][arow * 64 + aslot0 * 8] = o0;
        *(us16x8*)&As[b][arow * 64 + (aslot0 ^ 1) * 8] = o1;
    };

    issueA(0);
    stageB(0, 0);
    writeA(0);
    __syncthreads();
    int cur = 0;
    for (int kt = 0; kt < 5; ++kt) {
        int nxt = cur ^ 1;
        issueA(kt + 1);          // issue loads early (hide under MFMA)
        stageB(kt + 1, nxt);     // async direct-to-LDS
        do_mfma64(&As[cur][0], &Bs[cur][0], wr, wc, l, acc);
        writeA(nxt);             // write-late
        __syncthreads();         // one barrier per K-step
        cur = nxt;
    }
    do_mfma64(&As[cur][0], &Bs[cur][0], wr, wc, l, acc);

    // C write (layout: col = lane&15, row = (lane>>4)*4 + reg)
#pragma unroll
    for (int i = 0; i < 2; ++i) {
        int rw0 = m0 + wr * 32 + i * 16 + ((l >> 4) << 2);
#pragma unroll
        for (int j = 0; j < 4; ++j) {
            int col = n0 + wc * 64 + j * 16 + (l & 15);
#pragma unroll
            for (int r = 0; r < 4; ++r)
                H[(size_t)(rw0 + r) * DD + col] = f2bf(acc[i][j][r]);
        }
    }
    // fused column stats over this block's 64 rows
    float ls[4], ls2[4];
#pragma unroll
    for (int j = 0; j < 4; ++j) { ls[j] = 0.f; ls2[j] = 0.f; }
#pragma unroll
    for (int i = 0; i < 2; ++i)
#pragma unroll
        for (int j = 0; j < 4; ++j)
#pragma unroll
            for (int r = 0; r < 4; ++r) {
                float v = acc[i][j][r];
                ls[j] += v; ls2[j] += v * v;
            }
#pragma unroll
    for (int j = 0; j < 4; ++j) {
        ls[j]  += __shfl_xor(ls[j], 16);  ls[j]  += __shfl_xor(ls[j], 32);
        ls2[j] += __shfl_xor(ls2[j], 16); ls2[j] += __shfl_xor(ls2[j], 32);
    }
    if ((l >> 4) == 0) {
#pragma unroll
        for (int j = 0; j < 4; ++j) {
            sred[wr][wc][j * 16 + (l & 15)][0] = ls[j];
            sred[wr][wc][j * 16 + (l & 15)][1] = ls2[j];
        }
    }
    __syncthreads();
    if (tid < 128) {
        int wcx = tid >> 6, c64 = tid & 63;
        float sa = sred[0][wcx][c64][0] + sred[1][wcx][c64][0];
        float sb = sred[0][wcx][c64][1] + sred[1][wcx][c64][1];
        size_t pi = ((size_t)mblk * DD + n0 + tid) * 2;
        partial[pi] = sa; partial[pi + 1] = sb;
    }
}

// ---- GEMM2: H2(bf16) = act(BN(H1)) * B; BN+leaky fused into A-staging ----
__global__ __launch_bounds__(256) void gemmA(const u16* __restrict__ Hs,
                                             int rb0, int rb1, int M0, int M1, int M2,
                                             const u16* __restrict__ Bt,
                                             const float* __restrict__ alp,
                                             const float* __restrict__ mstats,
                                             u16* __restrict__ H2,
                                             float* __restrict__ partial, int mb) {
    __shared__ __align__(16) u16 As[2][4096];
    __shared__ __align__(16) u16 Bs[2][8192];
    __shared__ float sred[2][2][64][2];
    __shared__ __align__(16) float msL[768];
    int mblk, nb;
    if (!grid_decode(mb, mblk, nb)) return;
    const int m0 = mblk * 64, n0 = nb * 128;
    const int tid = threadIdx.x;
    const int w = tid >> 6, l = tid & 63;
    const int wr = w >> 1, wc = w & 1;
    const int lr8 = l >> 3, kpB = l & 7;
    const int arow = tid >> 2, kp0 = (tid & 3) * 2;
    const int aslot0 = kp0 ^ (arow & 7);

    const int seg = (m0 >= rb0) + (m0 >= rb1);
    const int segbase = seg == 0 ? 0 : seg == 1 ? rb0 : rb1;
    const int Mseg = seg == 0 ? M0 : seg == 1 ? M1 : M2;
    const int rloc = m0 - segbase + arow;
    const float al = *alp;

    if (tid < 192) ((f32x4*)msL)[tid] = ((const f32x4*)(mstats + seg * 768))[tid];

    f32x4 acc[2][4];
#pragma unroll
    for (int i = 0; i < 2; ++i)
#pragma unroll
        for (int j = 0; j < 4; ++j) acc[i][j] = f32x4{0.f, 0.f, 0.f, 0.f};

    us16x8 rh[2];
    auto issueA = [&](int kta) {
        rh[0] = us16x8{0, 0, 0, 0, 0, 0, 0, 0};
        rh[1] = us16x8{0, 0, 0, 0, 0, 0, 0, 0};
        if (rloc < Mseg) {
            const us16x8* sp = (const us16x8*)(Hs + (size_t)(m0 + arow) * DD + kta * 64 + kp0 * 8);
            rh[0] = sp[0]; rh[1] = sp[1];
        }
    };
    auto stageB = [&](int kta, int b) {
#pragma unroll
        for (int i = 0; i < 4; ++i) {
            int row = i * 32 + w * 8 + lr8;
            lds_load16(Bt + (size_t)(n0 + row) * DD + kta * 64 + (kpB ^ (row & 7)) * 8,
                       &Bs[b][i * 2048 + w * 512]);
        }
    };
    auto writeA = [&](int kta, int b) {
        int cb = kta * 64 + kp0 * 8;
        us16x8 o0 = {0, 0, 0, 0, 0, 0, 0, 0}, o1 = {0, 0, 0, 0, 0, 0, 0, 0};
        if (rloc < Mseg) {
            f32x4 sc0 = *(const f32x4*)&msL[cb];
            f32x4 sc1 = *(const f32x4*)&msL[cb + 4];
            f32x4 sc2 = *(const f32x4*)&msL[cb + 8];
            f32x4 sc3 = *(const f32x4*)&msL[cb + 12];
            f32x4 sh0 = *(const f32x4*)&msL[384 + cb];
            f32x4 sh1 = *(const f32x4*)&msL[384 + cb + 4];
            f32x4 sh2 = *(const f32x4*)&msL[384 + cb + 8];
            f32x4 sh3 = *(const f32x4*)&msL[384 + cb + 12];
            float v;
            v = bf2f(rh[0][0]) * sc0.x + sh0.x; v = v >= 0.f ? v : al * v; o0[0] = f2bf(v);
            v = bf2f(rh[0][1]) * sc0.y + sh0.y; v = v >= 0.f ? v : al * v; o0[1] = f2bf(v);
            v = bf2f(rh[0][2]) * sc0.z + sh0.z; v = v >= 0.f ? v : al * v; o0[2] = f2bf(v);
            v = bf2f(rh[0][3]) * sc0.w + sh0.w; v = v >= 0.f ? v : al * v; o0[3] = f2bf(v);
            v = bf2f(rh[0][4]) * sc1.x + sh1.x; v = v >= 0.f ? v : al * v; o0[4] = f2bf(v);
            v = bf2f(rh[0][5]) * sc1.y + sh1.y; v = v >= 0.f ? v : al * v; o0[5] = f2bf(v);
            v = bf2f(rh[0][6]) * sc1.z + sh1.z; v = v >= 0.f ? v : al * v; o0[6] = f2bf(v);
            v = bf2f(rh[0][7]) * sc1.w + sh1.w; v = v >= 0.f ? v : al * v; o0[7] = f2bf(v);
            v = bf2f(rh[1][0]) * sc2.x + sh2.x; v = v >= 0.f ? v : al * v; o1[0] = f2bf(v);
            v = bf2f(rh[1][1]) * sc2.y + sh2.y; v = v >= 0.f ? v : al * v; o1[1] = f2bf(v);
            v = bf2f(rh[1][2]) * sc2.z + sh2.z; v = v >= 0.f ? v : al * v; o1[2] = f2bf(v);
            v = bf2f(rh[1][3]) * sc2.w + sh2.w; v = v >= 0.f ? v : al * v; o1[3] = f2bf(v);
            v = bf2f(rh[1][4]) * sc3.x + sh3.x; v = v >= 0.f ? v : al * v; o1[4] = f2bf(v);
            v = bf2f(rh[1][5]) * sc3.y + sh3.y; v = v >= 0.f ? v : al * v; o1[5] = f2bf(v);
            v = bf2f(rh[1][6]) * sc3.z + sh3.z; v = v >= 0.f ? v : al * v; o1[6] = f2bf(v);
            v = bf2f(rh[1][7]) * sc3.w + sh3.w; v = v >= 0.f ? v : al * v; o1[7] = f2bf(v);
        }
        *(us16x8*)&As[b][arow * 64 + aslot0 * 8] = o0;
        *(us16x8*)&As[b][arow * 64 + (aslot0 ^ 1) * 8] = o1;
    };

    // prologue: msL must be visible to ALL waves before writeA reads it.
    issueA(0);
    stageB(0, 0);
    __syncthreads();      // msL visible; B0 staged
    writeA(0, 0);
    __syncthreads();      // A0 visible
    int cur = 0;
    for (int kt = 0; kt < 5; ++kt) {
        int nxt = cur ^ 1;
        issueA(kt + 1);
        stageB(kt + 1, nxt);
        do_mfma64(&As[cur][0], &Bs[cur][0], wr, wc, l, acc);
        writeA(kt + 1, nxt);
        __syncthreads();
        cur = nxt;
    }
    do_mfma64(&As[cur][0], &Bs[cur][0], wr, wc, l, acc);

#pragma unroll
    for (int i = 0; i < 2; ++i) {
        int rw0 = m0 + wr * 32 + i * 16 + ((l >> 4) << 2);
#pragma unroll
        for (int j = 0; j < 4; ++j) {
            int col = n0 + wc * 64 + j * 16 + (l & 15);
#pragma unroll
            for (int r = 0; r < 4; ++r)
                H2[(size_t)(rw0 + r) * DD + col] = f2bf(acc[i][j][r]);
        }
    }
    float ls[4], ls2[4];
#pragma unroll
    for (int j = 0; j < 4; ++j) { ls[j] = 0.f; ls2[j] = 0.f; }
#pragma unroll
    for (int i = 0; i < 2; ++i)
#pragma unroll
        for (int j = 0; j < 4; ++j)
#pragma unroll
            for (int r = 0; r < 4; ++r) {
                float v = acc[i][j][r];
                ls[j] += v; ls2[j] += v * v;
            }
#pragma unroll
    for (int j = 0; j < 4; ++j) {
        ls[j]  += __shfl_xor(ls[j], 16);  ls[j]  += __shfl_xor(ls[j], 32);
        ls2[j] += __shfl_xor(ls2[j], 16); ls2[j] += __shfl_xor(ls2[j], 32);
    }
    if ((l >> 4) == 0) {
#pragma unroll
        for (int j = 0; j < 4; ++j) {
            sred[wr][wc][j * 16 + (l & 15)][0] = ls[j];
            sred[wr][wc][j * 16 + (l & 15)][1] = ls2[j];
        }
    }
    __syncthreads();
    if (tid < 128) {
        int wcx = tid >> 6, c64 = tid & 63;
        float sa = sred[0][wcx][c64][0] + sred[1][wcx][c64][0];
        float sb = sred[0][wcx][c64][1] + sred[1][wcx][c64][1];
        size_t pi = ((size_t)mblk * DD + n0 + tid) * 2;
        partial[pi] = sa; partial[pi + 1] = sb;
    }
}

// ---- stats finalize, PARALLEL (standalone, used by pass A and BC-1) ----
__global__ void colfin(const float* __restrict__ partial, SegDesc s0, SegDesc s1,
                       SegDesc s2, const float* __restrict__ g,
                       const float* __restrict__ be, float* __restrict__ mstats) {
    int seg = blockIdx.x / 12, cg_ = blockIdx.x - seg * 12;
    SegDesc sd = (seg == 0) ? s0 : (seg == 1) ? s1 : s2;
    int tid = threadIdx.x;                 // 256
    int col = cg_ * 32 + (tid & 31);
    int part = tid >> 5;                   // 0..7
    float sa = 0.f, sb = 0.f;
    for (int b = sd.b0 + part; b < sd.b1; b += 8) {
        size_t pi = ((size_t)b * DD + col) * 2;
        sa += partial[pi]; sb += partial[pi + 1];
    }
    __shared__ float red[256][2];
    red[tid][0] = sa; red[tid][1] = sb;
    __syncthreads();
    for (int st = 128; st >= 32; st >>= 1) {
        if (tid < st) { red[tid][0] += red[tid + st][0]; red[tid][1] += red[tid + st][1]; }
        __syncthreads();
    }
    if (tid < 32) {
        float m = red[tid][0] * sd.invM;
        float var = fmaxf(red[tid][1] * sd.invM - m * m, 0.f);
        float iv = rsqrtf(var + 1e-5f);
        int c = cg_ * 32 + tid;
        float sc = iv * g[c];
        mstats[seg * 768 + c] = sc;
        mstats[seg * 768 + 384 + c] = be[c] - m * sc;
    }
}

// ---- final BN (+res) per segment -> f32 out, 4-wide (standalone: pass A) ----
__global__ void mlp_out_k(const u16* __restrict__ H, const float* __restrict__ mstats,
                          const float* __restrict__ res0, float* __restrict__ out0,
                          const float* __restrict__ res1, float* __restrict__ out1,
                          const float* __restrict__ res2, float* __restrict__ out2,
                          int rb0, int rb1, int M0, int M1, int M2) {
    int idx4 = blockIdx.x * 256 + threadIdx.x;
    int row = idx4 / 96, cq = idx4 - row * 96, col = cq * 4;
    int seg = (row >= rb0) + (row >= rb1);
    int vr = row - (seg == 1 ? rb0 : seg == 2 ? rb1 : 0);
    int M = seg == 0 ? M0 : seg == 1 ? M1 : M2;
    const float* res = seg == 0 ? res0 : seg == 1 ? res1 : res2;
    float* outf = seg == 0 ? out0 : seg == 1 ? out1 : out2;
    f32x4 v = {0.f, 0.f, 0.f, 0.f};
    if (vr < M) {
        us16x4 h = ((const us16x4*)H)[idx4];
        const float* ms = mstats + seg * 768;
        f32x4 sc = *(const f32x4*)(ms + col);
        f32x4 sh = *(const f32x4*)(ms + 384 + col);
        v.x = bf2f(h.x) * sc.x + sh.x;
        v.y = bf2f(h.y) * sc.y + sh.y;
        v.z = bf2f(h.z) * sc.z + sh.z;
        v.w = bf2f(h.w) * sc.w + sh.w;
        if (res) {
            f32x4 r = ((const f32x4*)res)[(size_t)vr * 96 + cq];
            v.x += r.x; v.y += r.y; v.z += r.z; v.w += r.w;
        }
    }
    ((f32x4*)outf)[(size_t)vr * 96 + cq] = v;
}

// ==== cooperative tail: colfin-BC2, mlp_out-BC, dist, enh, ep, cos, walk ====
struct TailArgs {
    const float* partial; SegDesc s0, s1, s2;
    const float* g2; const float* be2; float* mstats;
    const u16* H2;
    const float* res0; float* out0;   // epsI -> epsB
    const float* res1; float* out1;   // epqI -> epqB
    const float* res2; float* out2;   // dp0  -> dpfB
    int rb0, rb1, M0, M1, M2;
    const float* supC; const float* dsupC;
    float* dist; float* enh;
    float* outEp; float* npb;
    const float* qcls; float* eB; float* outW;
};

__global__ __launch_bounds__(256) void tail_k(TailArgs a) {
    cg::grid_group grid = cg::this_grid();
    const int bid = blockIdx.x;          // 375 blocks
    const int tid = threadIdx.x;         // 256
    const int wid = tid >> 6, l = tid & 63;
    __shared__ float red2[256][2];
    __shared__ float red1[256];
    __shared__ float sim[PP];
    __shared__ float wv[PP];
    __shared__ float sval[KK];
    __shared__ int   sidx[KK];
    __shared__ __align__(16) float epl[CC * DD];
    __shared__ float npl[CC];

    // ---- phase 0: colfin (pass-2 stats), 36 units ----
    if (bid < 36) {
        int seg = bid / 12, cgp = bid - seg * 12;
        SegDesc sd = (seg == 0) ? a.s0 : (seg == 1) ? a.s1 : a.s2;
        int col = cgp * 32 + (tid & 31);
        int part = tid >> 5;
        float sa = 0.f, sb = 0.f;
        for (int b = sd.b0 + part; b < sd.b1; b += 8) {
            size_t pi = ((size_t)b * DD + col) * 2;
            sa += a.partial[pi]; sb += a.partial[pi + 1];
        }
        red2[tid][0] = sa; red2[tid][1] = sb;
        __syncthreads();
        for (int st = 128; st >= 32; st >>= 1) {
            if (tid < st) { red2[tid][0] += red2[tid + st][0]; red2[tid][1] += red2[tid + st][1]; }
            __syncthreads();
        }
        if (tid < 32) {
            float m = red2[tid][0] * sd.invM;
            float var = fmaxf(red2[tid][1] * sd.invM - m * m, 0.f);
            float iv = rsqrtf(var + 1e-5f);
            int c = cgp * 32 + tid;
            float sc = iv * a.g2[c];
            a.mstats[seg * 768 + c] = sc;
            a.mstats[seg * 768 + 384 + c] = a.be2[c] - m * sc;
        }
    }
    grid.sync();

    // ---- phase 1: mlp_out-BC, grid-stride over 9312 chunks ----
    for (int chunk = bid; chunk < 9312; chunk += 375) {
        int idx4 = chunk * 256 + tid;
        int row = idx4 / 96, cq = idx4 - row * 96, col = cq * 4;
        int seg = (row >= a.rb0) + (row >= a.rb1);
        int vr = row - (seg == 1 ? a.rb0 : seg == 2 ? a.rb1 : 0);
        int M = seg == 0 ? a.M0 : seg == 1 ? a.M1 : a.M2;
        const float* res = seg == 0 ? a.res0 : seg == 1 ? a.res1 : a.res2;
        float* outf = seg == 0 ? a.out0 : seg == 1 ? a.out1 : a.out2;
        f32x4 v = {0.f, 0.f, 0.f, 0.f};
        if (vr < M) {
            us16x4 h = ((const us16x4*)a.H2)[idx4];
            const float* ms = a.mstats + seg * 768;
            f32x4 sc = *(const f32x4*)(ms + col);
            f32x4 sh = *(const f32x4*)(ms + 384 + col);
            v.x = bf2f(h.x) * sc.x + sh.x;
            v.y = bf2f(h.y) * sc.y + sh.y;
            v.z = bf2f(h.z) * sc.z + sh.z;
            v.w = bf2f(h.w) * sc.w + sh.w;
            f32x4 r = ((const f32x4*)res)[(size_t)vr * 96 + cq];
            v.x += r.x; v.y += r.y; v.z += r.z; v.w += r.w;
        }
        ((f32x4*)outf)[(size_t)vr * 96 + cq] = v;
    }
    grid.sync();

    // ---- phase 2: dist rows (9800), one wave per row, grid-stride ----
    for (int id = bid * 4 + wid; id < 2 * CC * SS * PP; id += 1500) {
        int b = id / (CC * SS * PP);
        int r = id - b * (CC * SS * PP);
        int cs = r / PP;
        const float* patch = b ? a.out2 : a.out0;
        const float* cls = b ? a.dsupC : a.supC;
        const float* pr = patch + (size_t)r * DD;
        const float* cr = cls + (size_t)cs * DD;
        float s = 0.f;
        for (int d = l; d < DD; d += 64) { float df = cr[d] - pr[d]; s += df * df; }
#pragma unroll
        for (int off = 32; off > 0; off >>= 1) s += __shfl_xor(s, off);
        if (l == 0) a.dist[id] = sqrtf(s);
    }
    grid.sync();

    // ---- phase 3: enh (50 units, rank-based top-30) ----
    if (bid < 50) {
        int b = bid / 25, cs = bid - b * 25, c = cs / SS;
        const float* db = a.dist + b * (CC * SS * PP);
        if (tid < PP) {
            float osum = 0.f;
            for (int cc = 0; cc < CC; ++cc) osum += db[cc * SS * PP + tid];
            float other = osum - db[c * SS * PP + tid];
            sim[tid] = db[cs * PP + tid] / (other + 1e-6f);
        }
        __syncthreads();
        if (tid < PP) {
            float mine = sim[tid];
            int cnt = 0;
            for (int p = 0; p < PP; ++p) {
                float v = sim[p];
                cnt += (v > mine) || (v == mine && p < tid);
            }
            if (cnt < KK) sidx[cnt] = tid;
        }
        __syncthreads();
        const float* patch = b ? a.out2 : a.out0;
        const float* cls = b ? a.dsupC : a.supC;
        for (int d = tid; d < DD; d += 256) {
            float sum = 0.f;
#pragma unroll
            for (int j = 0; j < KK; ++j) sum += patch[((size_t)cs * PP + sidx[j]) * DD + d];
            a.enh[(size_t)bid * DD + d] = 2.f * cls[(size_t)cs * DD + d] + sum * (1.f / 30.f);
        }
    }
    grid.sync();

    // ---- phase 4: ep (5 classes): mean of 10 enh rows + norms ----
    if (bid < CC) {
        int c = bid;
        float ss = 0.f;
        for (int t = tid; t < DD; t += 256) {
            float v = 0.f;
            for (int b = 0; b < 2; ++b)
                for (int s = 0; s < SS; ++s)
                    v += a.enh[((b * 25) + (c * SS + s)) * DD + t];
            v *= 0.1f;
            a.outEp[c * DD + t] = v;
            ss += v * v;
        }
        red1[tid] = ss;
        __syncthreads();
        for (int st = 128; st > 0; st >>= 1) {
            if (tid < st) red1[tid] += red1[tid + st];
            __syncthreads();
        }
        if (tid == 0) a.npb[c] = sqrtf(red1[0]);
    }
    grid.sync();

    // ---- phase 5: cos -> eB[c][row] = exp(cos-1), grid-stride rows ----
    for (int i = tid; i < CC * DD; i += 256) epl[i] = a.outEp[i];
    if (tid < CC) npl[tid] = a.npb[tid];
    __syncthreads();
    for (int row = bid * 4 + wid; row < QP; row += 1500) {
        const float4* rp = (const float4*)(a.out1 + (size_t)row * DD);
        const float4* e4 = (const float4*)epl;
        float nq = 0.f, dot[CC];
#pragma unroll
        for (int c = 0; c < CC; ++c) dot[c] = 0.f;
        for (int c4 = l; c4 < DD / 4; c4 += 64) {
            float4 x = rp[c4];
            nq += x.x * x.x + x.y * x.y + x.z * x.z + x.w * x.w;
#pragma unroll
            for (int c = 0; c < CC; ++c) {
                float4 e = e4[c * (DD / 4) + c4];
                dot[c] += e.x * x.x + e.y * x.y + e.z * x.z + e.w * x.w;
            }
        }
#pragma unroll
        for (int off = 32; off > 0; off >>= 1) {
            nq += __shfl_xor(nq, off);
#pragma unroll
            for (int c = 0; c < CC; ++c) dot[c] += __shfl_xor(dot[c], off);
        }
        if (l == 0) {
            float sq = sqrtf(nq);
#pragma unroll
            for (int c = 0; c < CC; ++c)
                a.eB[c * QP + row] = expf(dot[c] / fmaxf(npl[c] * sq, 1e-8f) - 1.f);
        }
    }
    grid.sync();

    // ---- phase 6: walk (375 units = c*75+q) ----
    {
        int c = bid / QQ, q = bid - c * QQ;
        float e = 0.f;
        if (tid < PP) { e = a.eB[c * QP + q * PP + tid]; wv[tid] = e; }
        red1[tid] = e;
        __syncthreads();
        for (int st = 128; st > 0; st >>= 1) {
            if (tid < st) red1[tid] += red1[tid + st];
            __syncthreads();
        }
        float inv = 1.f / red1[0];
        if (tid < PP) {
            int cnt = 0;
            for (int p = 0; p < PP; ++p) {
                float v = wv[p];
                cnt += (v > e) || (v == e && p < tid);
            }
            if (cnt < KK) { sval[cnt] = e * inv; sidx[cnt] = tid; }
        }
        __syncthreads();
        const float* eb = a.out1 + (size_t)q * PP * DD;
        for (int d = tid; d < DD; d += 256) {
            float acc = 0.f;
#pragma unroll
            for (int j = 0; j < KK; ++j) acc += sval[j] * eb[(size_t)sidx[j] * DD + d];
            a.outW[(size_t)bid * DD + d] = 2.f * a.qcls[q * DD + d] + acc;
        }
    }
}

extern "C" void kernel_launch(void* const* d_in, const int* in_sizes, int n_in,
                              void* d_out, int out_size, void* d_ws, size_t ws_size,
                              hipStream_t stream) {
    const float* sup   = (const float*)d_in[0];
    const float* qcls  = (const float*)d_in[1];
    const float* dsupI = (const float*)d_in[2];
    const float* epsI  = (const float*)d_in[3];
    const float* epqI  = (const float*)d_in[4];
    const float* dpI   = (const float*)d_in[5];
    const float* daW1 = (const float*)d_in[6],  *daG1 = (const float*)d_in[8],
               * daBe1 = (const float*)d_in[9], *daAl = (const float*)d_in[10];
    const float* daW2 = (const float*)d_in[11], *daG2 = (const float*)d_in[13],
               * daBe2 = (const float*)d_in[14];
    const float* paW1 = (const float*)d_in[15], *paG1 = (const float*)d_in[17],
               * paBe1 = (const float*)d_in[18], *paAl = (const float*)d_in[19];
    const float* paW2 = (const float*)d_in[20], *paG2 = (const float*)d_in[22],
               * paBe2 = (const float*)d_in[23];

    char* ws = (char*)d_ws;
    size_t off = 0;
    auto alloc = [&](size_t b) -> void* {
        void* p = ws + off;
        off = (off + b + 255) & ~(size_t)255;
        return p;
    };
    // row geometry (all 64-aligned so 64-row GEMM blocks stay within a segment)
    const int MP_S = 128;                  // dalle_sup: 25 valid
    const int M_P = 4900,  MP_P = 4992;    // patch batches
    const int M_Q = 14700, MP_Qa = 14848;  // query patches
    const int ROWS_A  = MP_S + MP_P;               // 5120
    const int ROWS_BC = MP_P + MP_Qa + MP_P;       // 24832
    const int RB0 = MP_P, RB1 = MP_P + MP_Qa;      // 4992, 19840

    u16*   wtAll = (u16*)alloc((size_t)4 * DD * DD * 2);
    u16*   wtDa1 = wtAll;
    u16*   wtDa2 = wtAll + DD * DD;
    u16*   wtPa1 = wtAll + 2 * DD * DD;
    u16*   wtPa2 = wtAll + 3 * DD * DD;
    u16*   hbuf  = (u16*)alloc((size_t)ROWS_BC * DD * 2);
    u16*   a2buf = (u16*)alloc((size_t)ROWS_BC * DD * 2);
    float* partial = (float*)alloc((size_t)(ROWS_BC / 64) * DD * 2 * 4);
    float* mstats  = (float*)alloc(3 * 768 * 4);
    float* dalleSup = (float*)alloc((size_t)MP_S * DD * 4);
    float* dp0   = (float*)alloc((size_t)MP_P * DD * 4);
    float* epsB  = (float*)alloc((size_t)MP_P * DD * 4);
    float* epqB  = (float*)alloc((size_t)MP_Qa * DD * 4);
    float* dpfB  = (float*)alloc((size_t)MP_P * DD * 4);
    float* distB = (float*)alloc((size_t)2 * CC * SS * PP * 4);
    float* enhB  = (float*)alloc((size_t)50 * DD * 4);
    float* npB   = (float*)alloc(64);
    float* eB    = (float*)alloc((size_t)CC * QP * 4);

    prep_w4<<<4 * 576, 256, 0, stream>>>(daW1, daW2, paW1, paW2, wtAll);

    // ---------- pass A (da): seg0 = dalle_emb_support(25), seg1 = dalle_patch(4900) ----------
    {
        int mb = ROWS_A / 64;                     // 80
        int nblk = ((mb + 7) / 8) * 24;           // 240
        SegDesc s0{0, 2, 1.f / 25.f}, s1{2, mb, 1.f / 4900.f}, sx{0, 0, 1.f};
        int g96 = (ROWS_A * 96) / 256;            // 1920
        gemmF<<<nblk, 256, 0, stream>>>(dsupI, dpI, nullptr, MP_S, ROWS_A,
                                        25, M_P, 0, wtDa1, hbuf, partial, mb);
        colfin<<<24, 256, 0, stream>>>(partial, s0, s1, sx, daG1, daBe1, mstats);
        gemmA<<<nblk, 256, 0, stream>>>(hbuf, MP_S, ROWS_A, 25, M_P, 0,
                                        wtDa2, daAl, mstats, a2buf, partial, mb);
        colfin<<<24, 256, 0, stream>>>(partial, s0, s1, sx, daG2, daBe2, mstats);
        mlp_out_k<<<g96, 256, 0, stream>>>(a2buf, mstats,
                                           nullptr, dalleSup,
                                           nullptr, dp0,
                                           nullptr, nullptr,
                                           MP_S, ROWS_A, 25, M_P, 0);
    }

    // ---------- pass BC (pa): seg0 = eps(4900), seg1 = epq(14700), seg2 = dalle_patch(4900) ----------
    {
        int mb = ROWS_BC / 64;                    // 388
        int nblk = ((mb + 7) / 8) * 24;           // 1176
        SegDesc s0{0, RB0 / 64, 1.f / 4900.f},
                s1{RB0 / 64, RB1 / 64, 1.f / 14700.f},
                s2{RB1 / 64, mb, 1.f / 4900.f};
        gemmF<<<nblk, 256, 0, stream>>>(epsI, epqI, dp0, RB0, RB1,
                                        M_P, M_Q, M_P, wtPa1, hbuf, partial, mb);
        colfin<<<36, 256, 0, stream>>>(partial, s0, s1, s2, paG1, paBe1, mstats);
        gemmA<<<nblk, 256, 0, stream>>>(hbuf, RB0, RB1, M_P, M_Q, M_P,
                                        wtPa2, paAl, mstats, a2buf, partial, mb);

        // ---------- cooperative tail: colfin2, mlp_out, dist, enh, ep, cos, walk ----------
        float* outEp = (float*)d_out;
        float* outW = (float*)d_out + CC * DD;
        TailArgs ta;
        ta.partial = partial; ta.s0 = s0; ta.s1 = s1; ta.s2 = s2;
        ta.g2 = paG2; ta.be2 = paBe2; ta.mstats = mstats;
        ta.H2 = a2buf;
        ta.res0 = epsI; ta.out0 = epsB;
        ta.res1 = epqI; ta.out1 = epqB;
        ta.res2 = dp0;  ta.out2 = dpfB;
        ta.rb0 = RB0; ta.rb1 = RB1; ta.M0 = M_P; ta.M1 = M_Q; ta.M2 = M_P;
        ta.supC = sup; ta.dsupC = dalleSup;
        ta.dist = distB; ta.enh = enhB;
        ta.outEp = outEp; ta.npb = npB;
        ta.qcls = qcls; ta.eB = eB; ta.outW = outW;
        void* kargs[] = {&ta};
        hipLaunchCooperativeKernel((const void*)tail_k, dim3(CC * QQ), dim3(256),
                                   kargs, 0, stream);
    }
}

// Round 12
// 355.216 us; speedup vs baseline: 1.2031x; 1.2031x over previous
//
#include <hip/hip_runtime.h>
#include <hip/hip_cooperative_groups.h>

namespace cg = cooperative_groups;

// EnhanceCls: 2 segmented MLP passes (64x128 dbuf GEMM tiles, fused BN-stats,
// BN+leaky fused into GEMM2 A-staging, parallel colfin, full-grid mlp_out) +
// ONE cooperative tail (grid=375, proven size) for the small L3-resident
// phases: dist, enh, ep, cos, walk. C=5 S=5 Q=75 P=196 D=384 K=30.

#define CC 5
#define SS 5
#define QQ 75
#define PP 196
#define DD 384
#define KK 30
#define QP (QQ * PP)   // 14700
#define TAILB (CC * QQ)  // 375 — proven cooperative launch size (R10)

typedef short bf16x8 __attribute__((ext_vector_type(8)));
typedef float f32x4  __attribute__((ext_vector_type(4)));
typedef unsigned short us16x4 __attribute__((ext_vector_type(4)));
typedef unsigned short us16x8 __attribute__((ext_vector_type(8)));
typedef unsigned short u16;

struct SegDesc { int b0, b1; float invM; };

__device__ __forceinline__ u16 f2bf(float f) {
    unsigned u = __float_as_uint(f);
    unsigned r = (u + 0x7fffu + ((u >> 16) & 1u)) >> 16;
    return (u16)r;
}
__device__ __forceinline__ float bf2f(u16 h) {
    return __uint_as_float((unsigned)h << 16);
}

__device__ __forceinline__ void lds_load16(const u16* g, u16* s) {
    __builtin_amdgcn_global_load_lds(
        (const __attribute__((address_space(1))) unsigned int*)g,
        (__attribute__((address_space(3))) unsigned int*)s, 16, 0, 0);
}

// XCD-aware decode: the 3 n-blocks of one m-block share bid%8 (same XCD).
__device__ __forceinline__ bool grid_decode(int mb, int& mblk, int& nb) {
    int bid = blockIdx.x;
    int g = bid / 24, t24 = bid - g * 24;
    nb = t24 >> 3;
    mblk = g * 8 + (t24 & 7);
    return mblk < mb;
}

// 64x128 tile: wave (wr,wc) computes rows wr*32..+32, cols wc*64..+64.
__device__ __forceinline__ void do_mfma64(const u16* Asb, const u16* Bsb,
                                          int wr, int wc, int l, f32x4 (&acc)[2][4]) {
#pragma unroll
    for (int ks = 0; ks < 2; ++ks) {
        bf16x8 af[2], bg[4];
#pragma unroll
        for (int i = 0; i < 2; ++i) {
            int rm = wr * 32 + i * 16 + (l & 15);
            af[i] = *(const bf16x8*)&Asb[rm * 64 + (((ks << 2) + (l >> 4)) ^ (rm & 7)) * 8];
        }
#pragma unroll
        for (int j = 0; j < 4; ++j) {
            int rn = wc * 64 + j * 16 + (l & 15);
            bg[j] = *(const bf16x8*)&Bsb[rn * 64 + (((ks << 2) + (l >> 4)) ^ (rn & 7)) * 8];
        }
#pragma unroll
        for (int i = 0; i < 2; ++i)
#pragma unroll
            for (int j = 0; j < 4; ++j)
                acc[i][j] = __builtin_amdgcn_mfma_f32_16x16x32_bf16(af[i], bg[j], acc[i][j], 0, 0, 0);
    }
}

// ---- weight prep: 4 matrices, Wt[m][n*384+k] = bf16(W[m][k*384+n]) ----
__global__ void prep_w4(const float* __restrict__ W0, const float* __restrict__ W1,
                        const float* __restrict__ W2, const float* __restrict__ W3,
                        u16* __restrict__ Wt) {
    int idx = blockIdx.x * 256 + threadIdx.x;      // 4 * 147456
    int m = idx / (DD * DD);
    int rem = idx - m * (DD * DD);
    int n = rem / DD, k = rem - n * DD;
    const float* W = (m == 0) ? W0 : (m == 1) ? W1 : (m == 2) ? W2 : W3;
    Wt[idx] = f2bf(W[k * DD + n]);
}

// ---- GEMM1: H(bf16) = bf16(A_f32) * B; 64x128 tile, dbuf pipeline ----
__global__ __launch_bounds__(256) void gemmF(const float* __restrict__ s0p,
                                             const float* __restrict__ s1p,
                                             const float* __restrict__ s2p,
                                             int rb0, int rb1, int M0, int M1, int M2,
                                             const u16* __restrict__ Bt,
                                             u16* __restrict__ H,
                                             float* __restrict__ partial, int mb) {
    __shared__ __align__(16) u16 As[2][4096];   // 64x64
    __shared__ __align__(16) u16 Bs[2][8192];   // 128x64
    __shared__ float sred[2][2][64][2];
    int mblk, nb;
    if (!grid_decode(mb, mblk, nb)) return;
    const int m0 = mblk * 64, n0 = nb * 128;
    const int tid = threadIdx.x;
    const int w = tid >> 6, l = tid & 63;
    const int wr = w >> 1, wc = w & 1;
    const int lr8 = l >> 3, kpB = l & 7;              // B staging coords
    const int arow = tid >> 2, kp0 = (tid & 3) * 2;   // A staging: 2 chunks/thread
    const int aslot0 = kp0 ^ (arow & 7);

    const int seg = (m0 >= rb0) + (m0 >= rb1);
    const float* src = seg == 0 ? s0p : seg == 1 ? s1p : s2p;
    const int segbase = seg == 0 ? 0 : seg == 1 ? rb0 : rb1;
    const int Mseg = seg == 0 ? M0 : seg == 1 ? M1 : M2;
    const int rloc = m0 - segbase + arow;

    f32x4 acc[2][4];
#pragma unroll
    for (int i = 0; i < 2; ++i)
#pragma unroll
        for (int j = 0; j < 4; ++j) acc[i][j] = f32x4{0.f, 0.f, 0.f, 0.f};

    f32x4 ra[4];
    auto issueA = [&](int kta) {
#pragma unroll
        for (int i = 0; i < 4; ++i) ra[i] = f32x4{0.f, 0.f, 0.f, 0.f};
        if (rloc < Mseg) {
            const f32x4* sp = (const f32x4*)(src + (size_t)rloc * DD + kta * 64 + kp0 * 8);
#pragma unroll
            for (int i = 0; i < 4; ++i) ra[i] = sp[i];
        }
    };
    auto stageB = [&](int kta, int b) {
#pragma unroll
        for (int i = 0; i < 4; ++i) {
            int row = i * 32 + w * 8 + lr8;
            lds_load16(Bt + (size_t)(n0 + row) * DD + kta * 64 + (kpB ^ (row & 7)) * 8,
                       &Bs[b][i * 2048 + w * 512]);
        }
    };
    auto writeA = [&](int b) {
        us16x8 o0, o1;
        o0[0] = f2bf(ra[0].x); o0[1] = f2bf(ra[0].y); o0[2] = f2bf(ra[0].z); o0[3] = f2bf(ra[0].w);
        o0[4] = f2bf(ra[1].x); o0[5] = f2bf(ra[1].y); o0[6] = f2bf(ra[1].z); o0[7] = f2bf(ra[1].w);
        o1[0] = f2bf(ra[2].x); o1[1] = f2bf(ra[2].y); o1[2] = f2bf(ra[2].z); o1[3] = f2bf(ra[2].w);
        o1[4] = f2bf(ra[3].x); o1[5] = f2bf(ra[3].y); o1[6] = f2bf(ra[3].z); o1[7] = f2bf(ra[3].w);
        *(us16x8*)&As[b][arow * 64 + aslot0 * 8] = o0;
        *(us16x8*)&As[b][arow * 64 + (aslot0 ^ 1) * 8] = o1;
    };

    issueA(0);
    stageB(0, 0);
    writeA(0);
    __syncthreads();
    int cur = 0;
    for (int kt = 0; kt < 5; ++kt) {
        int nxt = cur ^ 1;
        issueA(kt + 1);          // issue loads early (hide under MFMA)
        stageB(kt + 1, nxt);     // async direct-to-LDS
        do_mfma64(&As[cur][0], &Bs[cur][0], wr, wc, l, acc);
        writeA(nxt);             // write-late
        __syncthreads();         // one barrier per K-step
        cur = nxt;
    }
    do_mfma64(&As[cur][0], &Bs[cur][0], wr, wc, l, acc);

    // C write (layout: col = lane&15, row = (lane>>4)*4 + reg)
#pragma unroll
    for (int i = 0; i < 2; ++i) {
        int rw0 = m0 + wr * 32 + i * 16 + ((l >> 4) << 2);
#pragma unroll
        for (int j = 0; j < 4; ++j) {
            int col = n0 + wc * 64 + j * 16 + (l & 15);
#pragma unroll
            for (int r = 0; r < 4; ++r)
                H[(size_t)(rw0 + r) * DD + col] = f2bf(acc[i][j][r]);
        }
    }
    // fused column stats over this block's 64 rows
    float ls[4], ls2[4];
#pragma unroll
    for (int j = 0; j < 4; ++j) { ls[j] = 0.f; ls2[j] = 0.f; }
#pragma unroll
    for (int i = 0; i < 2; ++i)
#pragma unroll
        for (int j = 0; j < 4; ++j)
#pragma unroll
            for (int r = 0; r < 4; ++r) {
                float v = acc[i][j][r];
                ls[j] += v; ls2[j] += v * v;
            }
#pragma unroll
    for (int j = 0; j < 4; ++j) {
        ls[j]  += __shfl_xor(ls[j], 16);  ls[j]  += __shfl_xor(ls[j], 32);
        ls2[j] += __shfl_xor(ls2[j], 16); ls2[j] += __shfl_xor(ls2[j], 32);
    }
    if ((l >> 4) == 0) {
#pragma unroll
        for (int j = 0; j < 4; ++j) {
            sred[wr][wc][j * 16 + (l & 15)][0] = ls[j];
            sred[wr][wc][j * 16 + (l & 15)][1] = ls2[j];
        }
    }
    __syncthreads();
    if (tid < 128) {
        int wcx = tid >> 6, c64 = tid & 63;
        float sa = sred[0][wcx][c64][0] + sred[1][wcx][c64][0];
        float sb = sred[0][wcx][c64][1] + sred[1][wcx][c64][1];
        size_t pi = ((size_t)mblk * DD + n0 + tid) * 2;
        partial[pi] = sa; partial[pi + 1] = sb;
    }
}

// ---- GEMM2: H2(bf16) = act(BN(H1)) * B; BN+leaky fused into A-staging ----
__global__ __launch_bounds__(256) void gemmA(const u16* __restrict__ Hs,
                                             int rb0, int rb1, int M0, int M1, int M2,
                                             const u16* __restrict__ Bt,
                                             const float* __restrict__ alp,
                                             const float* __restrict__ mstats,
                                             u16* __restrict__ H2,
                                             float* __restrict__ partial, int mb) {
    __shared__ __align__(16) u16 As[2][4096];
    __shared__ __align__(16) u16 Bs[2][8192];
    __shared__ float sred[2][2][64][2];
    __shared__ __align__(16) float msL[768];
    int mblk, nb;
    if (!grid_decode(mb, mblk, nb)) return;
    const int m0 = mblk * 64, n0 = nb * 128;
    const int tid = threadIdx.x;
    const int w = tid >> 6, l = tid & 63;
    const int wr = w >> 1, wc = w & 1;
    const int lr8 = l >> 3, kpB = l & 7;
    const int arow = tid >> 2, kp0 = (tid & 3) * 2;
    const int aslot0 = kp0 ^ (arow & 7);

    const int seg = (m0 >= rb0) + (m0 >= rb1);
    const int segbase = seg == 0 ? 0 : seg == 1 ? rb0 : rb1;
    const int Mseg = seg == 0 ? M0 : seg == 1 ? M1 : M2;
    const int rloc = m0 - segbase + arow;
    const float al = *alp;

    if (tid < 192) ((f32x4*)msL)[tid] = ((const f32x4*)(mstats + seg * 768))[tid];

    f32x4 acc[2][4];
#pragma unroll
    for (int i = 0; i < 2; ++i)
#pragma unroll
        for (int j = 0; j < 4; ++j) acc[i][j] = f32x4{0.f, 0.f, 0.f, 0.f};

    us16x8 rh[2];
    auto issueA = [&](int kta) {
        rh[0] = us16x8{0, 0, 0, 0, 0, 0, 0, 0};
        rh[1] = us16x8{0, 0, 0, 0, 0, 0, 0, 0};
        if (rloc < Mseg) {
            const us16x8* sp = (const us16x8*)(Hs + (size_t)(m0 + arow) * DD + kta * 64 + kp0 * 8);
            rh[0] = sp[0]; rh[1] = sp[1];
        }
    };
    auto stageB = [&](int kta, int b) {
#pragma unroll
        for (int i = 0; i < 4; ++i) {
            int row = i * 32 + w * 8 + lr8;
            lds_load16(Bt + (size_t)(n0 + row) * DD + kta * 64 + (kpB ^ (row & 7)) * 8,
                       &Bs[b][i * 2048 + w * 512]);
        }
    };
    auto writeA = [&](int kta, int b) {
        int cb = kta * 64 + kp0 * 8;
        us16x8 o0 = {0, 0, 0, 0, 0, 0, 0, 0}, o1 = {0, 0, 0, 0, 0, 0, 0, 0};
        if (rloc < Mseg) {
            f32x4 sc0 = *(const f32x4*)&msL[cb];
            f32x4 sc1 = *(const f32x4*)&msL[cb + 4];
            f32x4 sc2 = *(const f32x4*)&msL[cb + 8];
            f32x4 sc3 = *(const f32x4*)&msL[cb + 12];
            f32x4 sh0 = *(const f32x4*)&msL[384 + cb];
            f32x4 sh1 = *(const f32x4*)&msL[384 + cb + 4];
            f32x4 sh2 = *(const f32x4*)&msL[384 + cb + 8];
            f32x4 sh3 = *(const f32x4*)&msL[384 + cb + 12];
            float v;
            v = bf2f(rh[0][0]) * sc0.x + sh0.x; v = v >= 0.f ? v : al * v; o0[0] = f2bf(v);
            v = bf2f(rh[0][1]) * sc0.y + sh0.y; v = v >= 0.f ? v : al * v; o0[1] = f2bf(v);
            v = bf2f(rh[0][2]) * sc0.z + sh0.z; v = v >= 0.f ? v : al * v; o0[2] = f2bf(v);
            v = bf2f(rh[0][3]) * sc0.w + sh0.w; v = v >= 0.f ? v : al * v; o0[3] = f2bf(v);
            v = bf2f(rh[0][4]) * sc1.x + sh1.x; v = v >= 0.f ? v : al * v; o0[4] = f2bf(v);
            v = bf2f(rh[0][5]) * sc1.y + sh1.y; v = v >= 0.f ? v : al * v; o0[5] = f2bf(v);
            v = bf2f(rh[0][6]) * sc1.z + sh1.z; v = v >= 0.f ? v : al * v; o0[6] = f2bf(v);
            v = bf2f(rh[0][7]) * sc1.w + sh1.w; v = v >= 0.f ? v : al * v; o0[7] = f2bf(v);
            v = bf2f(rh[1][0]) * sc2.x + sh2.x; v = v >= 0.f ? v : al * v; o1[0] = f2bf(v);
            v = bf2f(rh[1][1]) * sc2.y + sh2.y; v = v >= 0.f ? v : al * v; o1[1] = f2bf(v);
            v = bf2f(rh[1][2]) * sc2.z + sh2.z; v = v >= 0.f ? v : al * v; o1[2] = f2bf(v);
            v = bf2f(rh[1][3]) * sc2.w + sh2.w; v = v >= 0.f ? v : al * v; o1[3] = f2bf(v);
            v = bf2f(rh[1][4]) * sc3.x + sh3.x; v = v >= 0.f ? v : al * v; o1[4] = f2bf(v);
            v = bf2f(rh[1][5]) * sc3.y + sh3.y; v = v >= 0.f ? v : al * v; o1[5] = f2bf(v);
            v = bf2f(rh[1][6]) * sc3.z + sh3.z; v = v >= 0.f ? v : al * v; o1[6] = f2bf(v);
            v = bf2f(rh[1][7]) * sc3.w + sh3.w; v = v >= 0.f ? v : al * v; o1[7] = f2bf(v);
        }
        *(us16x8*)&As[b][arow * 64 + aslot0 * 8] = o0;
        *(us16x8*)&As[b][arow * 64 + (aslot0 ^ 1) * 8] = o1;
    };

    // prologue: msL must be visible to ALL waves before writeA reads it.
    issueA(0);
    stageB(0, 0);
    __syncthreads();      // msL visible; B0 staged
    writeA(0, 0);
    __syncthreads();      // A0 visible
    int cur = 0;
    for (int kt = 0; kt < 5; ++kt) {
        int nxt = cur ^ 1;
        issueA(kt + 1);
        stageB(kt + 1, nxt);
        do_mfma64(&As[cur][0], &Bs[cur][0], wr, wc, l, acc);
        writeA(kt + 1, nxt);
        __syncthreads();
        cur = nxt;
    }
    do_mfma64(&As[cur][0], &Bs[cur][0], wr, wc, l, acc);

#pragma unroll
    for (int i = 0; i < 2; ++i) {
        int rw0 = m0 + wr * 32 + i * 16 + ((l >> 4) << 2);
#pragma unroll
        for (int j = 0; j < 4; ++j) {
            int col = n0 + wc * 64 + j * 16 + (l & 15);
#pragma unroll
            for (int r = 0; r < 4; ++r)
                H2[(size_t)(rw0 + r) * DD + col] = f2bf(acc[i][j][r]);
        }
    }
    float ls[4], ls2[4];
#pragma unroll
    for (int j = 0; j < 4; ++j) { ls[j] = 0.f; ls2[j] = 0.f; }
#pragma unroll
    for (int i = 0; i < 2; ++i)
#pragma unroll
        for (int j = 0; j < 4; ++j)
#pragma unroll
            for (int r = 0; r < 4; ++r) {
                float v = acc[i][j][r];
                ls[j] += v; ls2[j] += v * v;
            }
#pragma unroll
    for (int j = 0; j < 4; ++j) {
        ls[j]  += __shfl_xor(ls[j], 16);  ls[j]  += __shfl_xor(ls[j], 32);
        ls2[j] += __shfl_xor(ls2[j], 16); ls2[j] += __shfl_xor(ls2[j], 32);
    }
    if ((l >> 4) == 0) {
#pragma unroll
        for (int j = 0; j < 4; ++j) {
            sred[wr][wc][j * 16 + (l & 15)][0] = ls[j];
            sred[wr][wc][j * 16 + (l & 15)][1] = ls2[j];
        }
    }
    __syncthreads();
    if (tid < 128) {
        int wcx = tid >> 6, c64 = tid & 63;
        float sa = sred[0][wcx][c64][0] + sred[1][wcx][c64][0];
        float sb = sred[0][wcx][c64][1] + sred[1][wcx][c64][1];
        size_t pi = ((size_t)mblk * DD + n0 + tid) * 2;
        partial[pi] = sa; partial[pi + 1] = sb;
    }
}

// ---- stats finalize, PARALLEL ----
__global__ void colfin(const float* __restrict__ partial, SegDesc s0, SegDesc s1,
                       SegDesc s2, const float* __restrict__ g,
                       const float* __restrict__ be, float* __restrict__ mstats) {
    int seg = blockIdx.x / 12, cg_ = blockIdx.x - seg * 12;
    SegDesc sd = (seg == 0) ? s0 : (seg == 1) ? s1 : s2;
    int tid = threadIdx.x;                 // 256
    int col = cg_ * 32 + (tid & 31);
    int part = tid >> 5;                   // 0..7
    float sa = 0.f, sb = 0.f;
    for (int b = sd.b0 + part; b < sd.b1; b += 8) {
        size_t pi = ((size_t)b * DD + col) * 2;
        sa += partial[pi]; sb += partial[pi + 1];
    }
    __shared__ float red[256][2];
    red[tid][0] = sa; red[tid][1] = sb;
    __syncthreads();
    for (int st = 128; st >= 32; st >>= 1) {
        if (tid < st) { red[tid][0] += red[tid + st][0]; red[tid][1] += red[tid + st][1]; }
        __syncthreads();
    }
    if (tid < 32) {
        float m = red[tid][0] * sd.invM;
        float var = fmaxf(red[tid][1] * sd.invM - m * m, 0.f);
        float iv = rsqrtf(var + 1e-5f);
        int c = cg_ * 32 + tid;
        float sc = iv * g[c];
        mstats[seg * 768 + c] = sc;
        mstats[seg * 768 + 384 + c] = be[c] - m * sc;
    }
}

// ---- final BN (+res) per segment -> f32 out, 4-wide ----
__global__ void mlp_out_k(const u16* __restrict__ H, const float* __restrict__ mstats,
                          const float* __restrict__ res0, float* __restrict__ out0,
                          const float* __restrict__ res1, float* __restrict__ out1,
                          const float* __restrict__ res2, float* __restrict__ out2,
                          int rb0, int rb1, int M0, int M1, int M2) {
    int idx4 = blockIdx.x * 256 + threadIdx.x;
    int row = idx4 / 96, cq = idx4 - row * 96, col = cq * 4;
    int seg = (row >= rb0) + (row >= rb1);
    int vr = row - (seg == 1 ? rb0 : seg == 2 ? rb1 : 0);
    int M = seg == 0 ? M0 : seg == 1 ? M1 : M2;
    const float* res = seg == 0 ? res0 : seg == 1 ? res1 : res2;
    float* outf = seg == 0 ? out0 : seg == 1 ? out1 : out2;
    f32x4 v = {0.f, 0.f, 0.f, 0.f};
    if (vr < M) {
        us16x4 h = ((const us16x4*)H)[idx4];
        const float* ms = mstats + seg * 768;
        f32x4 sc = *(const f32x4*)(ms + col);
        f32x4 sh = *(const f32x4*)(ms + 384 + col);
        v.x = bf2f(h.x) * sc.x + sh.x;
        v.y = bf2f(h.y) * sc.y + sh.y;
        v.z = bf2f(h.z) * sc.z + sh.z;
        v.w = bf2f(h.w) * sc.w + sh.w;
        if (res) {
            f32x4 r = ((const f32x4*)res)[(size_t)vr * 96 + cq];
            v.x += r.x; v.y += r.y; v.z += r.z; v.w += r.w;
        }
    }
    ((f32x4*)outf)[(size_t)vr * 96 + cq] = v;
}

// ==== cooperative tail (grid=375): dist, enh, ep, cos, walk ====
struct TailArgs {
    const float* epsB; const float* epqB; const float* dpfB;
    const float* supC; const float* dsupC;
    float* dist; float* enh;
    float* outEp; float* npb;
    const float* qcls; float* eB; float* outW;
};

__global__ __launch_bounds__(256) void tail_k(TailArgs a) {
    cg::grid_group grid = cg::this_grid();
    const int bid = blockIdx.x;          // 375 blocks
    const int tid = threadIdx.x;         // 256
    const int wid = tid >> 6, l = tid & 63;
    __shared__ float red1[256];
    __shared__ float sim[PP];
    __shared__ float wv[PP];
    __shared__ float sval[KK];
    __shared__ int   sidx[KK];
    __shared__ __align__(16) float epl[CC * DD];
    __shared__ float npl[CC];

    // ---- phase 0: dist rows (9800), one wave per row, grid-stride ----
    for (int id = bid * 4 + wid; id < 2 * CC * SS * PP; id += 1500) {
        int b = id / (CC * SS * PP);
        int r = id - b * (CC * SS * PP);
        int cs = r / PP;
        const float* patch = b ? a.dpfB : a.epsB;
        const float* cls = b ? a.dsupC : a.supC;
        const float* pr = patch + (size_t)r * DD;
        const float* cr = cls + (size_t)cs * DD;
        float s = 0.f;
        for (int d = l; d < DD; d += 64) { float df = cr[d] - pr[d]; s += df * df; }
#pragma unroll
        for (int off = 32; off > 0; off >>= 1) s += __shfl_xor(s, off);
        if (l == 0) a.dist[id] = sqrtf(s);
    }
    grid.sync();

    // ---- phase 1: enh (50 units, rank-based top-30) ----
    if (bid < 50) {
        int b = bid / 25, cs = bid - b * 25, c = cs / SS;
        const float* db = a.dist + b * (CC * SS * PP);
        if (tid < PP) {
            float osum = 0.f;
            for (int cc = 0; cc < CC; ++cc) osum += db[cc * SS * PP + tid];
            float other = osum - db[c * SS * PP + tid];
            sim[tid] = db[cs * PP + tid] / (other + 1e-6f);
        }
        __syncthreads();
        if (tid < PP) {
            float mine = sim[tid];
            int cnt = 0;
            for (int p = 0; p < PP; ++p) {
                float v = sim[p];
                cnt += (v > mine) || (v == mine && p < tid);
            }
            if (cnt < KK) sidx[cnt] = tid;
        }
        __syncthreads();
        const float* patch = b ? a.dpfB : a.epsB;
        const float* cls = b ? a.dsupC : a.supC;
        for (int d = tid; d < DD; d += 256) {
            float sum = 0.f;
#pragma unroll
            for (int j = 0; j < KK; ++j) sum += patch[((size_t)cs * PP + sidx[j]) * DD + d];
            a.enh[(size_t)bid * DD + d] = 2.f * cls[(size_t)cs * DD + d] + sum * (1.f / 30.f);
        }
    }
    grid.sync();

    // ---- phase 2: ep (5 classes): mean of 10 enh rows + norms ----
    if (bid < CC) {
        int c = bid;
        float ss = 0.f;
        for (int t = tid; t < DD; t += 256) {
            float v = 0.f;
            for (int b = 0; b < 2; ++b)
                for (int s = 0; s < SS; ++s)
                    v += a.enh[((b * 25) + (c * SS + s)) * DD + t];
            v *= 0.1f;
            a.outEp[c * DD + t] = v;
            ss += v * v;
        }
        red1[tid] = ss;
        __syncthreads();
        for (int st = 128; st > 0; st >>= 1) {
            if (tid < st) red1[tid] += red1[tid + st];
            __syncthreads();
        }
        if (tid == 0) a.npb[c] = sqrtf(red1[0]);
    }
    grid.sync();

    // ---- phase 3: cos -> eB[c][row] = exp(cos-1), grid-stride rows ----
    for (int i = tid; i < CC * DD; i += 256) epl[i] = a.outEp[i];
    if (tid < CC) npl[tid] = a.npb[tid];
    __syncthreads();
    for (int row = bid * 4 + wid; row < QP; row += 1500) {
        const float4* rp = (const float4*)(a.epqB + (size_t)row * DD);
        const float4* e4 = (const float4*)epl;
        float nq = 0.f, dot[CC];
#pragma unroll
        for (int c = 0; c < CC; ++c) dot[c] = 0.f;
        for (int c4 = l; c4 < DD / 4; c4 += 64) {
            float4 x = rp[c4];
            nq += x.x * x.x + x.y * x.y + x.z * x.z + x.w * x.w;
#pragma unroll
            for (int c = 0; c < CC; ++c) {
                float4 e = e4[c * (DD / 4) + c4];
                dot[c] += e.x * x.x + e.y * x.y + e.z * x.z + e.w * x.w;
            }
        }
#pragma unroll
        for (int off = 32; off > 0; off >>= 1) {
            nq += __shfl_xor(nq, off);
#pragma unroll
            for (int c = 0; c < CC; ++c) dot[c] += __shfl_xor(dot[c], off);
        }
        if (l == 0) {
            float sq = sqrtf(nq);
#pragma unroll
            for (int c = 0; c < CC; ++c)
                a.eB[c * QP + row] = expf(dot[c] / fmaxf(npl[c] * sq, 1e-8f) - 1.f);
        }
    }
    grid.sync();

    // ---- phase 4: walk (375 units = c*75+q) ----
    {
        int c = bid / QQ, q = bid - c * QQ;
        float e = 0.f;
        if (tid < PP) { e = a.eB[c * QP + q * PP + tid]; wv[tid] = e; }
        red1[tid] = e;
        __syncthreads();
        for (int st = 128; st > 0; st >>= 1) {
            if (tid < st) red1[tid] += red1[tid + st];
            __syncthreads();
        }
        float inv = 1.f / red1[0];
        if (tid < PP) {
            int cnt = 0;
            for (int p = 0; p < PP; ++p) {
                float v = wv[p];
                cnt += (v > e) || (v == e && p < tid);
            }
            if (cnt < KK) { sval[cnt] = e * inv; sidx[cnt] = tid; }
        }
        __syncthreads();
        const float* eb = a.epqB + (size_t)q * PP * DD;
        for (int d = tid; d < DD; d += 256) {
            float acc = 0.f;
#pragma unroll
            for (int j = 0; j < KK; ++j) acc += sval[j] * eb[(size_t)sidx[j] * DD + d];
            a.outW[(size_t)bid * DD + d] = 2.f * a.qcls[q * DD + d] + acc;
        }
    }
}

extern "C" void kernel_launch(void* const* d_in, const int* in_sizes, int n_in,
                              void* d_out, int out_size, void* d_ws, size_t ws_size,
                              hipStream_t stream) {
    const float* sup   = (const float*)d_in[0];
    const float* qcls  = (const float*)d_in[1];
    const float* dsupI = (const float*)d_in[2];
    const float* epsI  = (const float*)d_in[3];
    const float* epqI  = (const float*)d_in[4];
    const float* dpI   = (const float*)d_in[5];
    const float* daW1 = (const float*)d_in[6],  *daG1 = (const float*)d_in[8],
               * daBe1 = (const float*)d_in[9], *daAl = (const float*)d_in[10];
    const float* daW2 = (const float*)d_in[11], *daG2 = (const float*)d_in[13],
               * daBe2 = (const float*)d_in[14];
    const float* paW1 = (const float*)d_in[15], *paG1 = (const float*)d_in[17],
               * paBe1 = (const float*)d_in[18], *paAl = (const float*)d_in[19];
    const float* paW2 = (const float*)d_in[20], *paG2 = (const float*)d_in[22],
               * paBe2 = (const float*)d_in[23];

    char* ws = (char*)d_ws;
    size_t off = 0;
    auto alloc = [&](size_t b) -> void* {
        void* p = ws + off;
        off = (off + b + 255) & ~(size_t)255;
        return p;
    };
    // row geometry (all 64-aligned so 64-row GEMM blocks stay within a segment)
    const int MP_S = 128;                  // dalle_sup: 25 valid
    const int M_P = 4900,  MP_P = 4992;    // patch batches
    const int M_Q = 14700, MP_Qa = 14848;  // query patches
    const int ROWS_A  = MP_S + MP_P;               // 5120
    const int ROWS_BC = MP_P + MP_Qa + MP_P;       // 24832
    const int RB0 = MP_P, RB1 = MP_P + MP_Qa;      // 4992, 19840

    u16*   wtAll = (u16*)alloc((size_t)4 * DD * DD * 2);
    u16*   wtDa1 = wtAll;
    u16*   wtDa2 = wtAll + DD * DD;
    u16*   wtPa1 = wtAll + 2 * DD * DD;
    u16*   wtPa2 = wtAll + 3 * DD * DD;
    u16*   hbuf  = (u16*)alloc((size_t)ROWS_BC * DD * 2);
    u16*   a2buf = (u16*)alloc((size_t)ROWS_BC * DD * 2);
    float* partial = (float*)alloc((size_t)(ROWS_BC / 64) * DD * 2 * 4);
    float* mstats  = (float*)alloc(3 * 768 * 4);
    float* dalleSup = (float*)alloc((size_t)MP_S * DD * 4);
    float* dp0   = (float*)alloc((size_t)MP_P * DD * 4);
    float* epsB  = (float*)alloc((size_t)MP_P * DD * 4);
    float* epqB  = (float*)alloc((size_t)MP_Qa * DD * 4);
    float* dpfB  = (float*)alloc((size_t)MP_P * DD * 4);
    float* distB = (float*)alloc((size_t)2 * CC * SS * PP * 4);
    float* enhB  = (float*)alloc((size_t)50 * DD * 4);
    float* npB   = (float*)alloc(64);
    float* eB    = (float*)alloc((size_t)CC * QP * 4);

    prep_w4<<<4 * 576, 256, 0, stream>>>(daW1, daW2, paW1, paW2, wtAll);

    // ---------- pass A (da): seg0 = dalle_emb_support(25), seg1 = dalle_patch(4900) ----------
    {
        int mb = ROWS_A / 64;                     // 80
        int nblk = ((mb + 7) / 8) * 24;           // 240
        SegDesc s0{0, 2, 1.f / 25.f}, s1{2, mb, 1.f / 4900.f}, sx{0, 0, 1.f};
        int g96 = (ROWS_A * 96) / 256;            // 1920
        gemmF<<<nblk, 256, 0, stream>>>(dsupI, dpI, nullptr, MP_S, ROWS_A,
                                        25, M_P, 0, wtDa1, hbuf, partial, mb);
        colfin<<<24, 256, 0, stream>>>(partial, s0, s1, sx, daG1, daBe1, mstats);
        gemmA<<<nblk, 256, 0, stream>>>(hbuf, MP_S, ROWS_A, 25, M_P, 0,
                                        wtDa2, daAl, mstats, a2buf, partial, mb);
        colfin<<<24, 256, 0, stream>>>(partial, s0, s1, sx, daG2, daBe2, mstats);
        mlp_out_k<<<g96, 256, 0, stream>>>(a2buf, mstats,
                                           nullptr, dalleSup,
                                           nullptr, dp0,
                                           nullptr, nullptr,
                                           MP_S, ROWS_A, 25, M_P, 0);
    }

    // ---------- pass BC (pa): seg0 = eps(4900), seg1 = epq(14700), seg2 = dalle_patch(4900) ----------
    {
        int mb = ROWS_BC / 64;                    // 388
        int nblk = ((mb + 7) / 8) * 24;           // 1176
        SegDesc s0{0, RB0 / 64, 1.f / 4900.f},
                s1{RB0 / 64, RB1 / 64, 1.f / 14700.f},
                s2{RB1 / 64, mb, 1.f / 4900.f};
        int g96 = (ROWS_BC * 96) / 256;           // 9312
        gemmF<<<nblk, 256, 0, stream>>>(epsI, epqI, dp0, RB0, RB1,
                                        M_P, M_Q, M_P, wtPa1, hbuf, partial, mb);
        colfin<<<36, 256, 0, stream>>>(partial, s0, s1, s2, paG1, paBe1, mstats);
        gemmA<<<nblk, 256, 0, stream>>>(hbuf, RB0, RB1, M_P, M_Q, M_P,
                                        wtPa2, paAl, mstats, a2buf, partial, mb);
        colfin<<<36, 256, 0, stream>>>(partial, s0, s1, s2, paG2, paBe2, mstats);
        mlp_out_k<<<g96, 256, 0, stream>>>(a2buf, mstats,
                                           epsI, epsB,
                                           epqI, epqB,
                                           dp0, dpfB,
                                           RB0, RB1, M_P, M_Q, M_P);
    }

    // ---------- cooperative tail (375 blocks): dist, enh, ep, cos, walk ----------
    {
        float* outEp = (float*)d_out;
        float* outW = (float*)d_out + CC * DD;
        TailArgs ta;
        ta.epsB = epsB; ta.epqB = epqB; ta.dpfB = dpfB;
        ta.supC = sup; ta.dsupC = dalleSup;
        ta.dist = distB; ta.enh = enhB;
        ta.outEp = outEp; ta.npb = npB;
        ta.qcls = qcls; ta.eB = eB; ta.outW = outW;
        void* kargs[] = {&ta};
        hipLaunchCooperativeKernel((const void*)tail_k, dim3(TAILB), dim3(256),
                                   kargs, 0, stream);
    }
}

// Round 13
// 177.040 us; speedup vs baseline: 2.4140x; 2.0064x over previous
//
#include <hip/hip_runtime.h>

// EnhanceCls: 2 segmented MLP passes. 64x128 GEMM tiles (4 waves, dbuf
// single-barrier K-loop); GEMM2 fuses BN+leaky into A-staging; parallel
// column-stats finalize. Separate small tail launches (cooperative grid.sync
// measured at ~45us/sync on MI355X -- R10/R12 -- so coop fusion loses).
// C=5 S=5 Q=75 P=196 D=384 K=30.

#define CC 5
#define SS 5
#define QQ 75
#define PP 196
#define DD 384
#define KK 30
#define QP (QQ * PP)   // 14700

typedef short bf16x8 __attribute__((ext_vector_type(8)));
typedef float f32x4  __attribute__((ext_vector_type(4)));
typedef unsigned short us16x4 __attribute__((ext_vector_type(4)));
typedef unsigned short us16x8 __attribute__((ext_vector_type(8)));
typedef unsigned short u16;

struct SegDesc { int b0, b1; float invM; };

__device__ __forceinline__ u16 f2bf(float f) {
    unsigned u = __float_as_uint(f);
    unsigned r = (u + 0x7fffu + ((u >> 16) & 1u)) >> 16;
    return (u16)r;
}
__device__ __forceinline__ float bf2f(u16 h) {
    return __uint_as_float((unsigned)h << 16);
}

__device__ __forceinline__ void lds_load16(const u16* g, u16* s) {
    __builtin_amdgcn_global_load_lds(
        (const __attribute__((address_space(1))) unsigned int*)g,
        (__attribute__((address_space(3))) unsigned int*)s, 16, 0, 0);
}

// XCD-aware decode: the 3 n-blocks of one m-block share bid%8 (same XCD).
__device__ __forceinline__ bool grid_decode(int mb, int& mblk, int& nb) {
    int bid = blockIdx.x;
    int g = bid / 24, t24 = bid - g * 24;
    nb = t24 >> 3;
    mblk = g * 8 + (t24 & 7);
    return mblk < mb;
}

// 64x128 tile: wave (wr,wc) computes rows wr*32..+32, cols wc*64..+64.
__device__ __forceinline__ void do_mfma64(const u16* Asb, const u16* Bsb,
                                          int wr, int wc, int l, f32x4 (&acc)[2][4]) {
#pragma unroll
    for (int ks = 0; ks < 2; ++ks) {
        bf16x8 af[2], bg[4];
#pragma unroll
        for (int i = 0; i < 2; ++i) {
            int rm = wr * 32 + i * 16 + (l & 15);
            af[i] = *(const bf16x8*)&Asb[rm * 64 + (((ks << 2) + (l >> 4)) ^ (rm & 7)) * 8];
        }
#pragma unroll
        for (int j = 0; j < 4; ++j) {
            int rn = wc * 64 + j * 16 + (l & 15);
            bg[j] = *(const bf16x8*)&Bsb[rn * 64 + (((ks << 2) + (l >> 4)) ^ (rn & 7)) * 8];
        }
#pragma unroll
        for (int i = 0; i < 2; ++i)
#pragma unroll
            for (int j = 0; j < 4; ++j)
                acc[i][j] = __builtin_amdgcn_mfma_f32_16x16x32_bf16(af[i], bg[j], acc[i][j], 0, 0, 0);
    }
}

// ---- weight prep: 4 matrices, Wt[m][n*384+k] = bf16(W[m][k*384+n]) ----
__global__ void prep_w4(const float* __restrict__ W0, const float* __restrict__ W1,
                        const float* __restrict__ W2, const float* __restrict__ W3,
                        u16* __restrict__ Wt) {
    int idx = blockIdx.x * 256 + threadIdx.x;      // 4 * 147456
    int m = idx / (DD * DD);
    int rem = idx - m * (DD * DD);
    int n = rem / DD, k = rem - n * DD;
    const float* W = (m == 0) ? W0 : (m == 1) ? W1 : (m == 2) ? W2 : W3;
    Wt[idx] = f2bf(W[k * DD + n]);
}

// ---- GEMM1: H(bf16) = bf16(A_f32) * B; 64x128 tile, dbuf pipeline ----
__global__ __launch_bounds__(256) void gemmF(const float* __restrict__ s0p,
                                             const float* __restrict__ s1p,
                                             const float* __restrict__ s2p,
                                             int rb0, int rb1, int M0, int M1, int M2,
                                             const u16* __restrict__ Bt,
                                             u16* __restrict__ H,
                                             float* __restrict__ partial, int mb) {
    __shared__ __align__(16) u16 As[2][4096];   // 64x64
    __shared__ __align__(16) u16 Bs[2][8192];   // 128x64
    __shared__ float sred[2][2][64][2];
    int mblk, nb;
    if (!grid_decode(mb, mblk, nb)) return;
    const int m0 = mblk * 64, n0 = nb * 128;
    const int tid = threadIdx.x;
    const int w = tid >> 6, l = tid & 63;
    const int wr = w >> 1, wc = w & 1;
    const int lr8 = l >> 3, kpB = l & 7;              // B staging coords
    const int arow = tid >> 2, kp0 = (tid & 3) * 2;   // A staging: 2 chunks/thread
    const int aslot0 = kp0 ^ (arow & 7);

    const int seg = (m0 >= rb0) + (m0 >= rb1);
    const float* src = seg == 0 ? s0p : seg == 1 ? s1p : s2p;
    const int segbase = seg == 0 ? 0 : seg == 1 ? rb0 : rb1;
    const int Mseg = seg == 0 ? M0 : seg == 1 ? M1 : M2;
    const int rloc = m0 - segbase + arow;

    f32x4 acc[2][4];
#pragma unroll
    for (int i = 0; i < 2; ++i)
#pragma unroll
        for (int j = 0; j < 4; ++j) acc[i][j] = f32x4{0.f, 0.f, 0.f, 0.f};

    f32x4 ra[4];
    auto issueA = [&](int kta) {
#pragma unroll
        for (int i = 0; i < 4; ++i) ra[i] = f32x4{0.f, 0.f, 0.f, 0.f};
        if (rloc < Mseg) {
            const f32x4* sp = (const f32x4*)(src + (size_t)rloc * DD + kta * 64 + kp0 * 8);
#pragma unroll
            for (int i = 0; i < 4; ++i) ra[i] = sp[i];
        }
    };
    auto stageB = [&](int kta, int b) {
#pragma unroll
        for (int i = 0; i < 4; ++i) {
            int row = i * 32 + w * 8 + lr8;
            lds_load16(Bt + (size_t)(n0 + row) * DD + kta * 64 + (kpB ^ (row & 7)) * 8,
                       &Bs[b][i * 2048 + w * 512]);
        }
    };
    auto writeA = [&](int b) {
        us16x8 o0, o1;
        o0[0] = f2bf(ra[0].x); o0[1] = f2bf(ra[0].y); o0[2] = f2bf(ra[0].z); o0[3] = f2bf(ra[0].w);
        o0[4] = f2bf(ra[1].x); o0[5] = f2bf(ra[1].y); o0[6] = f2bf(ra[1].z); o0[7] = f2bf(ra[1].w);
        o1[0] = f2bf(ra[2].x); o1[1] = f2bf(ra[2].y); o1[2] = f2bf(ra[2].z); o1[3] = f2bf(ra[2].w);
        o1[4] = f2bf(ra[3].x); o1[5] = f2bf(ra[3].y); o1[6] = f2bf(ra[3].z); o1[7] = f2bf(ra[3].w);
        *(us16x8*)&As[b][arow * 64 + aslot0 * 8] = o0;
        *(us16x8*)&As[b][arow * 64 + (aslot0 ^ 1) * 8] = o1;
    };

    issueA(0);
    stageB(0, 0);
    writeA(0);
    __syncthreads();
    int cur = 0;
    for (int kt = 0; kt < 5; ++kt) {
        int nxt = cur ^ 1;
        issueA(kt + 1);          // issue loads early (hide under MFMA)
        stageB(kt + 1, nxt);     // async direct-to-LDS
        do_mfma64(&As[cur][0], &Bs[cur][0], wr, wc, l, acc);
        writeA(nxt);             // write-late
        __syncthreads();         // one barrier per K-step
        cur = nxt;
    }
    do_mfma64(&As[cur][0], &Bs[cur][0], wr, wc, l, acc);

    // C write (layout: col = lane&15, row = (lane>>4)*4 + reg)
#pragma unroll
    for (int i = 0; i < 2; ++i) {
        int rw0 = m0 + wr * 32 + i * 16 + ((l >> 4) << 2);
#pragma unroll
        for (int j = 0; j < 4; ++j) {
            int col = n0 + wc * 64 + j * 16 + (l & 15);
#pragma unroll
            for (int r = 0; r < 4; ++r)
                H[(size_t)(rw0 + r) * DD + col] = f2bf(acc[i][j][r]);
        }
    }
    // fused column stats over this block's 64 rows
    float ls[4], ls2[4];
#pragma unroll
    for (int j = 0; j < 4; ++j) { ls[j] = 0.f; ls2[j] = 0.f; }
#pragma unroll
    for (int i = 0; i < 2; ++i)
#pragma unroll
        for (int j = 0; j < 4; ++j)
#pragma unroll
            for (int r = 0; r < 4; ++r) {
                float v = acc[i][j][r];
                ls[j] += v; ls2[j] += v * v;
            }
#pragma unroll
    for (int j = 0; j < 4; ++j) {
        ls[j]  += __shfl_xor(ls[j], 16);  ls[j]  += __shfl_xor(ls[j], 32);
        ls2[j] += __shfl_xor(ls2[j], 16); ls2[j] += __shfl_xor(ls2[j], 32);
    }
    if ((l >> 4) == 0) {
#pragma unroll
        for (int j = 0; j < 4; ++j) {
            sred[wr][wc][j * 16 + (l & 15)][0] = ls[j];
            sred[wr][wc][j * 16 + (l & 15)][1] = ls2[j];
        }
    }
    __syncthreads();
    if (tid < 128) {
        int wcx = tid >> 6, c64 = tid & 63;
        float sa = sred[0][wcx][c64][0] + sred[1][wcx][c64][0];
        float sb = sred[0][wcx][c64][1] + sred[1][wcx][c64][1];
        size_t pi = ((size_t)mblk * DD + n0 + tid) * 2;
        partial[pi] = sa; partial[pi + 1] = sb;
    }
}

// ---- GEMM2: H2(bf16) = act(BN(H1)) * B; BN+leaky fused into A-staging ----
__global__ __launch_bounds__(256) void gemmA(const u16* __restrict__ Hs,
                                             int rb0, int rb1, int M0, int M1, int M2,
                                             const u16* __restrict__ Bt,
                                             const float* __restrict__ alp,
                                             const float* __restrict__ mstats,
                                             u16* __restrict__ H2,
                                             float* __restrict__ partial, int mb) {
    __shared__ __align__(16) u16 As[2][4096];
    __shared__ __align__(16) u16 Bs[2][8192];
    __shared__ float sred[2][2][64][2];
    __shared__ __align__(16) float msL[768];
    int mblk, nb;
    if (!grid_decode(mb, mblk, nb)) return;
    const int m0 = mblk * 64, n0 = nb * 128;
    const int tid = threadIdx.x;
    const int w = tid >> 6, l = tid & 63;
    const int wr = w >> 1, wc = w & 1;
    const int lr8 = l >> 3, kpB = l & 7;
    const int arow = tid >> 2, kp0 = (tid & 3) * 2;
    const int aslot0 = kp0 ^ (arow & 7);

    const int seg = (m0 >= rb0) + (m0 >= rb1);
    const int segbase = seg == 0 ? 0 : seg == 1 ? rb0 : rb1;
    const int Mseg = seg == 0 ? M0 : seg == 1 ? M1 : M2;
    const int rloc = m0 - segbase + arow;
    const float al = *alp;

    if (tid < 192) ((f32x4*)msL)[tid] = ((const f32x4*)(mstats + seg * 768))[tid];

    f32x4 acc[2][4];
#pragma unroll
    for (int i = 0; i < 2; ++i)
#pragma unroll
        for (int j = 0; j < 4; ++j) acc[i][j] = f32x4{0.f, 0.f, 0.f, 0.f};

    us16x8 rh[2];
    auto issueA = [&](int kta) {
        rh[0] = us16x8{0, 0, 0, 0, 0, 0, 0, 0};
        rh[1] = us16x8{0, 0, 0, 0, 0, 0, 0, 0};
        if (rloc < Mseg) {
            const us16x8* sp = (const us16x8*)(Hs + (size_t)(m0 + arow) * DD + kta * 64 + kp0 * 8);
            rh[0] = sp[0]; rh[1] = sp[1];
        }
    };
    auto stageB = [&](int kta, int b) {
#pragma unroll
        for (int i = 0; i < 4; ++i) {
            int row = i * 32 + w * 8 + lr8;
            lds_load16(Bt + (size_t)(n0 + row) * DD + kta * 64 + (kpB ^ (row & 7)) * 8,
                       &Bs[b][i * 2048 + w * 512]);
        }
    };
    auto writeA = [&](int kta, int b) {
        int cb = kta * 64 + kp0 * 8;
        us16x8 o0 = {0, 0, 0, 0, 0, 0, 0, 0}, o1 = {0, 0, 0, 0, 0, 0, 0, 0};
        if (rloc < Mseg) {
            f32x4 sc0 = *(const f32x4*)&msL[cb];
            f32x4 sc1 = *(const f32x4*)&msL[cb + 4];
            f32x4 sc2 = *(const f32x4*)&msL[cb + 8];
            f32x4 sc3 = *(const f32x4*)&msL[cb + 12];
            f32x4 sh0 = *(const f32x4*)&msL[384 + cb];
            f32x4 sh1 = *(const f32x4*)&msL[384 + cb + 4];
            f32x4 sh2 = *(const f32x4*)&msL[384 + cb + 8];
            f32x4 sh3 = *(const f32x4*)&msL[384 + cb + 12];
            float v;
            v = bf2f(rh[0][0]) * sc0.x + sh0.x; v = v >= 0.f ? v : al * v; o0[0] = f2bf(v);
            v = bf2f(rh[0][1]) * sc0.y + sh0.y; v = v >= 0.f ? v : al * v; o0[1] = f2bf(v);
            v = bf2f(rh[0][2]) * sc0.z + sh0.z; v = v >= 0.f ? v : al * v; o0[2] = f2bf(v);
            v = bf2f(rh[0][3]) * sc0.w + sh0.w; v = v >= 0.f ? v : al * v; o0[3] = f2bf(v);
            v = bf2f(rh[0][4]) * sc1.x + sh1.x; v = v >= 0.f ? v : al * v; o0[4] = f2bf(v);
            v = bf2f(rh[0][5]) * sc1.y + sh1.y; v = v >= 0.f ? v : al * v; o0[5] = f2bf(v);
            v = bf2f(rh[0][6]) * sc1.z + sh1.z; v = v >= 0.f ? v : al * v; o0[6] = f2bf(v);
            v = bf2f(rh[0][7]) * sc1.w + sh1.w; v = v >= 0.f ? v : al * v; o0[7] = f2bf(v);
            v = bf2f(rh[1][0]) * sc2.x + sh2.x; v = v >= 0.f ? v : al * v; o1[0] = f2bf(v);
            v = bf2f(rh[1][1]) * sc2.y + sh2.y; v = v >= 0.f ? v : al * v; o1[1] = f2bf(v);
            v = bf2f(rh[1][2]) * sc2.z + sh2.z; v = v >= 0.f ? v : al * v; o1[2] = f2bf(v);
            v = bf2f(rh[1][3]) * sc2.w + sh2.w; v = v >= 0.f ? v : al * v; o1[3] = f2bf(v);
            v = bf2f(rh[1][4]) * sc3.x + sh3.x; v = v >= 0.f ? v : al * v; o1[4] = f2bf(v);
            v = bf2f(rh[1][5]) * sc3.y + sh3.y; v = v >= 0.f ? v : al * v; o1[5] = f2bf(v);
            v = bf2f(rh[1][6]) * sc3.z + sh3.z; v = v >= 0.f ? v : al * v; o1[6] = f2bf(v);
            v = bf2f(rh[1][7]) * sc3.w + sh3.w; v = v >= 0.f ? v : al * v; o1[7] = f2bf(v);
        }
        *(us16x8*)&As[b][arow * 64 + aslot0 * 8] = o0;
        *(us16x8*)&As[b][arow * 64 + (aslot0 ^ 1) * 8] = o1;
    };

    // prologue: msL must be visible to ALL waves before writeA reads it.
    issueA(0);
    stageB(0, 0);
    __syncthreads();      // msL visible; B0 staged
    writeA(0, 0);
    __syncthreads();      // A0 visible
    int cur = 0;
    for (int kt = 0; kt < 5; ++kt) {
        int nxt = cur ^ 1;
        issueA(kt + 1);
        stageB(kt + 1, nxt);
        do_mfma64(&As[cur][0], &Bs[cur][0], wr, wc, l, acc);
        writeA(kt + 1, nxt);
        __syncthreads();
        cur = nxt;
    }
    do_mfma64(&As[cur][0], &Bs[cur][0], wr, wc, l, acc);

#pragma unroll
    for (int i = 0; i < 2; ++i) {
        int rw0 = m0 + wr * 32 + i * 16 + ((l >> 4) << 2);
#pragma unroll
        for (int j = 0; j < 4; ++j) {
            int col = n0 + wc * 64 + j * 16 + (l & 15);
#pragma unroll
            for (int r = 0; r < 4; ++r)
                H2[(size_t)(rw0 + r) * DD + col] = f2bf(acc[i][j][r]);
        }
    }
    float ls[4], ls2[4];
#pragma unroll
    for (int j = 0; j < 4; ++j) { ls[j] = 0.f; ls2[j] = 0.f; }
#pragma unroll
    for (int i = 0; i < 2; ++i)
#pragma unroll
        for (int j = 0; j < 4; ++j)
#pragma unroll
            for (int r = 0; r < 4; ++r) {
                float v = acc[i][j][r];
                ls[j] += v; ls2[j] += v * v;
            }
#pragma unroll
    for (int j = 0; j < 4; ++j) {
        ls[j]  += __shfl_xor(ls[j], 16);  ls[j]  += __shfl_xor(ls[j], 32);
        ls2[j] += __shfl_xor(ls2[j], 16); ls2[j] += __shfl_xor(ls2[j], 32);
    }
    if ((l >> 4) == 0) {
#pragma unroll
        for (int j = 0; j < 4; ++j) {
            sred[wr][wc][j * 16 + (l & 15)][0] = ls[j];
            sred[wr][wc][j * 16 + (l & 15)][1] = ls2[j];
        }
    }
    __syncthreads();
    if (tid < 128) {
        int wcx = tid >> 6, c64 = tid & 63;
        float sa = sred[0][wcx][c64][0] + sred[1][wcx][c64][0];
        float sb = sred[0][wcx][c64][1] + sred[1][wcx][c64][1];
        size_t pi = ((size_t)mblk * DD + n0 + tid) * 2;
        partial[pi] = sa; partial[pi + 1] = sb;
    }
}

// ---- stats finalize, PARALLEL: grid = nseg*12 blocks (32 cols each) x 256
// threads (8 partial-stripes per col). sc = iv*g, sh = be - m*sc ----
__global__ void colfin(const float* __restrict__ partial, SegDesc s0, SegDesc s1,
                       SegDesc s2, const float* __restrict__ g,
                       const float* __restrict__ be, float* __restrict__ mstats) {
    int seg = blockIdx.x / 12, cg_ = blockIdx.x - seg * 12;
    SegDesc sd = (seg == 0) ? s0 : (seg == 1) ? s1 : s2;
    int tid = threadIdx.x;                 // 256
    int col = cg_ * 32 + (tid & 31);
    int part = tid >> 5;                   // 0..7
    float sa = 0.f, sb = 0.f;
    for (int b = sd.b0 + part; b < sd.b1; b += 8) {
        size_t pi = ((size_t)b * DD + col) * 2;
        sa += partial[pi]; sb += partial[pi + 1];
    }
    __shared__ float red[256][2];
    red[tid][0] = sa; red[tid][1] = sb;
    __syncthreads();
    for (int st = 128; st >= 32; st >>= 1) {
        if (tid < st) { red[tid][0] += red[tid + st][0]; red[tid][1] += red[tid + st][1]; }
        __syncthreads();
    }
    if (tid < 32) {
        float m = red[tid][0] * sd.invM;
        float var = fmaxf(red[tid][1] * sd.invM - m * m, 0.f);
        float iv = rsqrtf(var + 1e-5f);
        int c = cg_ * 32 + tid;
        float sc = iv * g[c];
        mstats[seg * 768 + c] = sc;
        mstats[seg * 768 + 384 + c] = be[c] - m * sc;
    }
}

// ---- final BN (+res) per segment -> f32 out, 4-wide ----
__global__ void mlp_out_k(const u16* __restrict__ H, const float* __restrict__ mstats,
                          const float* __restrict__ res0, float* __restrict__ out0,
                          const float* __restrict__ res1, float* __restrict__ out1,
                          const float* __restrict__ res2, float* __restrict__ out2,
                          int rb0, int rb1, int M0, int M1, int M2) {
    int idx4 = blockIdx.x * 256 + threadIdx.x;
    int row = idx4 / 96, cq = idx4 - row * 96, col = cq * 4;
    int seg = (row >= rb0) + (row >= rb1);
    int vr = row - (seg == 1 ? rb0 : seg == 2 ? rb1 : 0);
    int M = seg == 0 ? M0 : seg == 1 ? M1 : M2;
    const float* res = seg == 0 ? res0 : seg == 1 ? res1 : res2;
    float* outf = seg == 0 ? out0 : seg == 1 ? out1 : out2;
    f32x4 v = {0.f, 0.f, 0.f, 0.f};
    if (vr < M) {
        us16x4 h = ((const us16x4*)H)[idx4];
        const float* ms = mstats + seg * 768;
        f32x4 sc = *(const f32x4*)(ms + col);
        f32x4 sh = *(const f32x4*)(ms + 384 + col);
        v.x = bf2f(h.x) * sc.x + sh.x;
        v.y = bf2f(h.y) * sc.y + sh.y;
        v.z = bf2f(h.z) * sc.z + sh.z;
        v.w = bf2f(h.w) * sc.w + sh.w;
        if (res) {
            f32x4 r = ((const f32x4*)res)[(size_t)vr * 96 + cq];
            v.x += r.x; v.y += r.y; v.z += r.z; v.w += r.w;
        }
    }
    ((f32x4*)outf)[(size_t)vr * 96 + cq] = v;
}

// ---- dist[b][cs][p] = ||cls[cs]-patch[cs,p]||  (1 wave per row) ----
__global__ void dist_k(const float* __restrict__ epsP, const float* __restrict__ dpfP,
                       const float* __restrict__ supC, const float* __restrict__ dsupC,
                       float* __restrict__ dist) {
    int id = blockIdx.x;               // 0..9799
    int b = id / (CC * SS * PP);
    int r = id - b * (CC * SS * PP);   // cs*196+p
    int cs = r / PP;
    const float* patch = b ? dpfP : epsP;
    const float* cls = b ? dsupC : supC;
    int l = threadIdx.x;  // 64
    const float* pr = patch + (size_t)r * DD;
    const float* cr = cls + (size_t)cs * DD;
    float s = 0.f;
    for (int d = l; d < DD; d += 64) { float df = cr[d] - pr[d]; s += df * df; }
#pragma unroll
    for (int off = 32; off > 0; off >>= 1) s += __shfl_xor(s, off);
    if (l == 0) dist[id] = sqrtf(s);
}

// ---- enhance: sim = dist/(other+1e-6), rank-based top-30, mean of selected ----
__global__ void enh_k(const float* __restrict__ dist, const float* __restrict__ epsP,
                      const float* __restrict__ dpfP, const float* __restrict__ supC,
                      const float* __restrict__ dsupC, float* __restrict__ enh) {
    int id = blockIdx.x;          // 0..49 = b*25+cs
    int b = id / 25, cs = id - b * 25, c = cs / SS;
    int t = threadIdx.x;          // 384
    __shared__ float sim[PP];
    __shared__ int sidx[KK];
    const float* db = dist + b * (CC * SS * PP);
    if (t < PP) {
        float osum = 0.f;
        for (int cc = 0; cc < CC; ++cc) osum += db[cc * SS * PP + t];   // d0 (s=0) rows
        float other = osum - db[c * SS * PP + t];
        sim[t] = db[cs * PP + t] / (other + 1e-6f);
    }
    __syncthreads();
    if (t < PP) {
        float mine = sim[t];
        int cnt = 0;
        for (int p = 0; p < PP; ++p) {
            float v = sim[p];
            cnt += (v > mine) || (v == mine && p < t);
        }
        if (cnt < KK) sidx[cnt] = t;     // rank unique -> no race
    }
    __syncthreads();
    const float* patch = b ? dpfP : epsP;
    const float* cls = b ? dsupC : supC;
    float sum = 0.f;
#pragma unroll
    for (int j = 0; j < KK; ++j) sum += patch[((size_t)cs * PP + sidx[j]) * DD + t];
    enh[(size_t)id * DD + t] = 2.f * cls[(size_t)cs * DD + t] + sum * (1.f / 30.f);
}

// ---- ep[c] = mean over 10 enh rows; also prototype norms ----
__global__ void ep_k(const float* __restrict__ enh, float* __restrict__ outEp,
                     float* __restrict__ npb) {
    int t = threadIdx.x;  // 384
    __shared__ float red[DD];
    for (int c = 0; c < CC; ++c) {
        float v = 0.f;
        for (int b = 0; b < 2; ++b)
            for (int s = 0; s < SS; ++s)
                v += enh[((b * 25) + (c * SS + s)) * DD + t];
        v *= 0.1f;
        outEp[c * DD + t] = v;
        red[t] = v * v;
        __syncthreads();
        if (t < 64) {
            float s = 0.f;
            for (int i = t; i < DD; i += 64) s += red[i];
#pragma unroll
            for (int off = 32; off > 0; off >>= 1) s += __shfl_xor(s, off);
            if (t == 0) npb[c] = sqrtf(s);
        }
        __syncthreads();
    }
}

// ---- eB[c][row] = exp(cos(proto_c, patch_row) - 1): coalesced float4 reads ----
__global__ void cos_k(const float* __restrict__ epq, const float* __restrict__ ep,
                      const float* __restrict__ npb, float* __restrict__ eB) {
    __shared__ __align__(16) float epl[CC * DD];
    __shared__ float npl[CC];
    int t = threadIdx.x;  // 256
    for (int i = t; i < CC * DD; i += 256) epl[i] = ep[i];
    if (t < CC) npl[t] = npb[t];
    __syncthreads();
    int wid = t >> 6, l = t & 63;
    int row = blockIdx.x * 4 + wid;           // 3675*4 = 14700 exactly
    const float4* rp = (const float4*)(epq + (size_t)row * DD);
    const float4* e4 = (const float4*)epl;
    float nq = 0.f, dot[CC];
#pragma unroll
    for (int c = 0; c < CC; ++c) dot[c] = 0.f;
    for (int c4 = l; c4 < DD / 4; c4 += 64) {
        float4 x = rp[c4];
        nq += x.x * x.x + x.y * x.y + x.z * x.z + x.w * x.w;
#pragma unroll
        for (int c = 0; c < CC; ++c) {
            float4 e = e4[c * (DD / 4) + c4];
            dot[c] += e.x * x.x + e.y * x.y + e.z * x.z + e.w * x.w;
        }
    }
#pragma unroll
    for (int off = 32; off > 0; off >>= 1) {
        nq += __shfl_xor(nq, off);
#pragma unroll
        for (int c = 0; c < CC; ++c) dot[c] += __shfl_xor(dot[c], off);
    }
    if (l == 0) {
        float sq = sqrtf(nq);
#pragma unroll
        for (int c = 0; c < CC; ++c)
            eB[c * QP + row] = expf(dot[c] / fmaxf(npl[c] * sq, 1e-8f) - 1.f);
    }
}

// ---- per-(c,q): normalize e, rank-based top-30, weighted-sum gather ----
__global__ void walk2_k(const float* __restrict__ eB, const float* __restrict__ epq,
                        const float* __restrict__ qcls, float* __restrict__ outp) {
    int bid = blockIdx.x;         // c*75+q
    int c = bid / QQ, q = bid - c * QQ;
    int t = threadIdx.x;          // 256
    __shared__ float wv[PP];
    __shared__ float red[256];
    __shared__ float sval[KK];
    __shared__ int sidx[KK];
    float e = 0.f;
    if (t < PP) { e = eB[c * QP + q * PP + t]; wv[t] = e; }
    red[t] = e;
    __syncthreads();
    for (int st = 128; st > 0; st >>= 1) { if (t < st) red[t] += red[t + st]; __syncthreads(); }
    float inv = 1.f / red[0];
    if (t < PP) {
        int cnt = 0;
        for (int p = 0; p < PP; ++p) {
            float v = wv[p];
            cnt += (v > e) || (v == e && p < t);
        }
        if (cnt < KK) { sval[cnt] = e * inv; sidx[cnt] = t; }
    }
    __syncthreads();
    const float* eb = epq + (size_t)q * PP * DD;
    for (int d = t; d < DD; d += 256) {
        float a = 0.f;
#pragma unroll
        for (int j = 0; j < KK; ++j) a += sval[j] * eb[(size_t)sidx[j] * DD + d];
        outp[(size_t)bid * DD + d] = 2.f * qcls[q * DD + d] + a;
    }
}

extern "C" void kernel_launch(void* const* d_in, const int* in_sizes, int n_in,
                              void* d_out, int out_size, void* d_ws, size_t ws_size,
                              hipStream_t stream) {
    const float* sup   = (const float*)d_in[0];
    const float* qcls  = (const float*)d_in[1];
    const float* dsupI = (const float*)d_in[2];
    const float* epsI  = (const float*)d_in[3];
    const float* epqI  = (const float*)d_in[4];
    const float* dpI   = (const float*)d_in[5];
    const float* daW1 = (const float*)d_in[6],  *daG1 = (const float*)d_in[8],
               * daBe1 = (const float*)d_in[9], *daAl = (const float*)d_in[10];
    const float* daW2 = (const float*)d_in[11], *daG2 = (const float*)d_in[13],
               * daBe2 = (const float*)d_in[14];
    const float* paW1 = (const float*)d_in[15], *paG1 = (const float*)d_in[17],
               * paBe1 = (const float*)d_in[18], *paAl = (const float*)d_in[19];
    const float* paW2 = (const float*)d_in[20], *paG2 = (const float*)d_in[22],
               * paBe2 = (const float*)d_in[23];

    char* ws = (char*)d_ws;
    size_t off = 0;
    auto alloc = [&](size_t b) -> void* {
        void* p = ws + off;
        off = (off + b + 255) & ~(size_t)255;
        return p;
    };
    // row geometry (all 64-aligned so 64-row GEMM blocks stay within a segment)
    const int MP_S = 128;                  // dalle_sup: 25 valid
    const int M_P = 4900,  MP_P = 4992;    // patch batches
    const int M_Q = 14700, MP_Qa = 14848;  // query patches
    const int ROWS_A  = MP_S + MP_P;               // 5120
    const int ROWS_BC = MP_P + MP_Qa + MP_P;       // 24832
    const int RB0 = MP_P, RB1 = MP_P + MP_Qa;      // 4992, 19840

    u16*   wtAll = (u16*)alloc((size_t)4 * DD * DD * 2);
    u16*   wtDa1 = wtAll;
    u16*   wtDa2 = wtAll + DD * DD;
    u16*   wtPa1 = wtAll + 2 * DD * DD;
    u16*   wtPa2 = wtAll + 3 * DD * DD;
    u16*   hbuf  = (u16*)alloc((size_t)ROWS_BC * DD * 2);
    u16*   a2buf = (u16*)alloc((size_t)ROWS_BC * DD * 2);
    float* partial = (float*)alloc((size_t)(ROWS_BC / 64) * DD * 2 * 4);
    float* mstats  = (float*)alloc(3 * 768 * 4);
    float* dalleSup = (float*)alloc((size_t)MP_S * DD * 4);
    float* dp0   = (float*)alloc((size_t)MP_P * DD * 4);
    float* epsB  = (float*)alloc((size_t)MP_P * DD * 4);
    float* epqB  = (float*)alloc((size_t)MP_Qa * DD * 4);
    float* dpfB  = (float*)alloc((size_t)MP_P * DD * 4);
    float* distB = (float*)alloc((size_t)2 * CC * SS * PP * 4);
    float* enhB  = (float*)alloc((size_t)50 * DD * 4);
    float* npB   = (float*)alloc(64);
    float* eB    = (float*)alloc((size_t)CC * QP * 4);

    prep_w4<<<4 * 576, 256, 0, stream>>>(daW1, daW2, paW1, paW2, wtAll);

    // ---------- pass A (da): seg0 = dalle_emb_support(25), seg1 = dalle_patch(4900) ----------
    {
        int mb = ROWS_A / 64;                     // 80
        int nblk = ((mb + 7) / 8) * 24;           // 240
        SegDesc s0{0, 2, 1.f / 25.f}, s1{2, mb, 1.f / 4900.f}, sx{0, 0, 1.f};
        int g96 = (ROWS_A * 96) / 256;            // 1920
        gemmF<<<nblk, 256, 0, stream>>>(dsupI, dpI, nullptr, MP_S, ROWS_A,
                                        25, M_P, 0, wtDa1, hbuf, partial, mb);
        colfin<<<24, 256, 0, stream>>>(partial, s0, s1, sx, daG1, daBe1, mstats);
        gemmA<<<nblk, 256, 0, stream>>>(hbuf, MP_S, ROWS_A, 25, M_P, 0,
                                        wtDa2, daAl, mstats, a2buf, partial, mb);
        colfin<<<24, 256, 0, stream>>>(partial, s0, s1, sx, daG2, daBe2, mstats);
        mlp_out_k<<<g96, 256, 0, stream>>>(a2buf, mstats,
                                           nullptr, dalleSup,
                                           nullptr, dp0,
                                           nullptr, nullptr,
                                           MP_S, ROWS_A, 25, M_P, 0);
    }

    // ---------- pass BC (pa): seg0 = eps(4900), seg1 = epq(14700), seg2 = dalle_patch(4900, f32 dp0) ----------
    {
        int mb = ROWS_BC / 64;                    // 388
        int nblk = ((mb + 7) / 8) * 24;           // 1176
        SegDesc s0{0, RB0 / 64, 1.f / 4900.f},
                s1{RB0 / 64, RB1 / 64, 1.f / 14700.f},
                s2{RB1 / 64, mb, 1.f / 4900.f};
        int g96 = (ROWS_BC * 96) / 256;           // 9312
        gemmF<<<nblk, 256, 0, stream>>>(epsI, epqI, dp0, RB0, RB1,
                                        M_P, M_Q, M_P, wtPa1, hbuf, partial, mb);
        colfin<<<36, 256, 0, stream>>>(partial, s0, s1, s2, paG1, paBe1, mstats);
        gemmA<<<nblk, 256, 0, stream>>>(hbuf, RB0, RB1, M_P, M_Q, M_P,
                                        wtPa2, paAl, mstats, a2buf, partial, mb);
        colfin<<<36, 256, 0, stream>>>(partial, s0, s1, s2, paG2, paBe2, mstats);
        mlp_out_k<<<g96, 256, 0, stream>>>(a2buf, mstats,
                                           epsI, epsB,
                                           epqI, epqB,
                                           dp0, dpfB,
                                           RB0, RB1, M_P, M_Q, M_P);
    }

    // ---------- enhancement ----------
    dist_k<<<2 * CC * SS * PP, 64, 0, stream>>>(epsB, dpfB, sup, dalleSup, distB);
    enh_k<<<2 * CC * SS, 384, 0, stream>>>(distB, epsB, dpfB, sup, dalleSup, enhB);

    float* outEp = (float*)d_out;
    float* outW = (float*)d_out + CC * DD;
    ep_k<<<1, 384, 0, stream>>>(enhB, outEp, npB);

    // ---------- feature walk ----------
    cos_k<<<QP / 4, 256, 0, stream>>>(epqB, outEp, npB, eB);
    walk2_k<<<CC * QQ, 256, 0, stream>>>(eB, epqB, qcls, outW);
}